// Round 6
// baseline (2024.662 us; speedup 1.0000x reference)
//
#include <hip/hip_runtime.h>
#include <math.h>

#define L_ 8
#define D_ 1024
#define H_ 16
#define HK_ 4
#define DH_ 64
#define F_ 2816
#define V_ 32000
#define T_ 1024
#define B_ 2
#define M_ (B_*T_)          // 2048 tokens
#define SCALE_ 0.125f       // DH^-0.5

typedef unsigned short u16;
typedef unsigned int   u32;
typedef __attribute__((ext_vector_type(4))) float  f32x4;
typedef __attribute__((ext_vector_type(8))) short  bf16x8;   // 8 bf16 = 4 VGPRs (MFMA A/B frag)
typedef __attribute__((ext_vector_type(4))) unsigned short u16x4;
typedef __attribute__((ext_vector_type(4))) unsigned int   u32x4;

__device__ __forceinline__ float bf2f(u16 h) {
    union { u32 u; float f; } v; v.u = ((u32)h) << 16; return v.f;
}
__device__ __forceinline__ u16 f2bf(float f) {   // round-to-nearest-even
    union { float f; u32 u; } v; v.f = f;
    u32 r = v.u + 0x7fffu + ((v.u >> 16) & 1u);
    return (u16)(r >> 16);
}

__device__ __forceinline__ void gl_lds16(const void* g, void* l) {
    __builtin_amdgcn_global_load_lds(
        (const __attribute__((address_space(1))) unsigned int*)g,
        (__attribute__((address_space(3))) unsigned int*)l,
        16, 0, 0);
}

template<int N> __device__ __forceinline__ void vm_wait() {
    if constexpr (N == 0) asm volatile("s_waitcnt vmcnt(0)" ::: "memory");
    else if constexpr (N == 3) asm volatile("s_waitcnt vmcnt(3)" ::: "memory");
    else if constexpr (N == 4) asm volatile("s_waitcnt vmcnt(4)" ::: "memory");
    else if constexpr (N == 6) asm volatile("s_waitcnt vmcnt(6)" ::: "memory");
    else if constexpr (N == 8) asm volatile("s_waitcnt vmcnt(8)" ::: "memory");
}

// ---------------------------------------------------------------------------
// gemm3: counted-vmcnt triple-buffered GEMM. C[M,N]=A[M,K] x W[N,K]^T (bf16).
// BN=128, BK=32, 4 waves 2x2, bijective XCD swizzle, global_load_lds staging.
// Per iter: stage tile t+2, wait vmcnt(2*LPT) (tile t landed; t+1/t+2 stay in
// flight), RAW s_barrier (no vmcnt drain!), compute, lgkmcnt(0)+s_barrier.
// EPI: 0 = bf16 store, 1 = f32 store, 2 = f32 +=,
//      3 = fused SiLU (w1/w3 row-interleaved; even col=h1, odd=h3 -> hh[M][F_])
//      4 = fused RoPE (QKV: cols<1280 rotated via tables) -> bf16 [M][N]
// ---------------------------------------------------------------------------
template<int BM, int EPI>
__global__ __launch_bounds__(256)
void gemm3_k(const u16* __restrict__ A, int K,
             const u16* __restrict__ W, int N,
             float* __restrict__ Of, u16* __restrict__ Ob,
             const float* __restrict__ tc, const float* __restrict__ ts)
{
    constexpr int FM = BM / 32;
    constexpr int FN = 4;
    constexpr int GM = M_ / BM;
    constexpr int IPA = BM / 64;
    constexpr int LPT = IPA + 2;          // loads per tile per wave
    __shared__ u16 sA[3 * BM * 32];
    __shared__ u16 sB[3 * 128 * 32];

    const int tid  = threadIdx.x;
    const int lane = tid & 63, wv = tid >> 6;
    const int wm = wv >> 1, wn = wv & 1;
    const int l15 = lane & 15, lhi = lane >> 4;
    const int m0 = wm * (BM / 2), n0 = wn * 64;

    const int nwg = gridDim.x;
    const int q8 = nwg >> 3, r8 = nwg & 7;
    const int xcd = blockIdx.x & 7, off8 = blockIdx.x >> 3;
    const int wgid = (xcd < r8 ? xcd * (q8 + 1) : r8 * (q8 + 1) + (xcd - r8) * q8) + off8;
    const int tM = wgid % GM, tN = wgid / GM;

    const int srow = lane >> 2;
    const int scol = (lane & 3) * 8;

    const u16* Abase = A + (size_t)(tM * BM) * K;
    const u16* Wbase = W + (size_t)(tN * 128) * K;

    f32x4 acc[FM][FN];
#pragma unroll
    for (int i = 0; i < FM; ++i)
#pragma unroll
        for (int j = 0; j < FN; ++j) acc[i][j] = f32x4{0.f, 0.f, 0.f, 0.f};

    auto stage = [&](int t, int buf) {
        const int kt = t << 5;
        u16* sa = sA + buf * (BM * 32);
        u16* sb = sB + buf * (128 * 32);
#pragma unroll
        for (int i = 0; i < IPA; ++i) {
            int c = wv * IPA + i;
            gl_lds16(Abase + (size_t)(c * 16 + srow) * K + kt + scol, sa + c * 512);
        }
#pragma unroll
        for (int i = 0; i < 2; ++i) {
            int c = wv * 2 + i;
            gl_lds16(Wbase + (size_t)(c * 16 + srow) * K + kt + scol, sb + c * 512);
        }
    };

    const int nt = K >> 5;                // >= 32 for all users
    stage(0, 0);
    stage(1, 1);

    for (int t = 0; t < nt; ++t) {
        if (t + 2 < nt) { stage(t + 2, (t + 2) % 3); vm_wait<2 * LPT>(); }
        else if (t + 1 < nt) vm_wait<LPT>();
        else vm_wait<0>();
        __builtin_amdgcn_s_barrier();     // tile t visible to all waves

        const u16* sa = sA + (t % 3) * (BM * 32);
        const u16* sb = sB + (t % 3) * (128 * 32);
        bf16x8 av[FM], bv[FN];
#pragma unroll
        for (int i = 0; i < FM; ++i)
            av[i] = *(const bf16x8*)&sa[(m0 + i * 16 + l15) * 32 + lhi * 8];
#pragma unroll
        for (int j = 0; j < FN; ++j)
            bv[j] = *(const bf16x8*)&sb[(n0 + j * 16 + l15) * 32 + lhi * 8];
#pragma unroll
        for (int i = 0; i < FM; ++i)
#pragma unroll
            for (int j = 0; j < FN; ++j)
                acc[i][j] = __builtin_amdgcn_mfma_f32_16x16x32_bf16(
                    av[i], bv[j], acc[i][j], 0, 0, 0);

        if (t + 1 < nt) {
            asm volatile("s_waitcnt lgkmcnt(0)" ::: "memory");
            __builtin_amdgcn_s_barrier(); // buf (t%3) free for stage(t+3)
        }
    }

    // epilogue: D col = lane&15, row = (lane>>4)*4 + reg
#pragma unroll
    for (int i = 0; i < FM; ++i)
#pragma unroll
        for (int j = 0; j < FN; ++j) {
            size_t gm = (size_t)tM * BM + m0 + i * 16 + lhi * 4;
            size_t gn = (size_t)tN * 128 + n0 + j * 16 + l15;
#pragma unroll
            for (int r = 0; r < 4; ++r) {
                float v = acc[i][j][r];
                size_t idx = (gm + r) * (size_t)N + gn;
                if (EPI == 0) {
                    Ob[idx] = f2bf(v);
                } else if (EPI == 1) {
                    Of[idx] = v;
                } else if (EPI == 2) {
                    Of[idx] += v;
                } else if (EPI == 3) {
                    float b = __shfl_xor(v, 1);
                    if ((lane & 1) == 0) {
                        float s = v / (1.0f + expf(-v));
                        Ob[(gm + r) * (size_t)F_ + (gn >> 1)] = f2bf(s * b);
                    }
                } else {   // EPI == 4: RoPE on q (cols<1024) and k (1024..1280)
                    float b = __shfl_xor(v, 1);
                    if ((int)gn < 1280) {
                        int dd = (int)gn & 63;
                        int jj = dd >> 1;
                        int tt = (int)(gm + r) & (T_ - 1);
                        float c = tc[tt * 32 + jj], s = ts[tt * 32 + jj];
                        float ro = ((dd & 1) == 0) ? (v * c - b * s) : (b * s + v * c);
                        Ob[idx] = f2bf(ro);
                    } else {
                        Ob[idx] = f2bf(v);
                    }
                }
            }
        }
}

// f32 -> bf16 layer-strided conversion
__global__ __launch_bounds__(256)
void cvt_k(const float* __restrict__ src, u16* __restrict__ dst,
           unsigned long long sStride, unsigned long long dStride)
{
    int l = blockIdx.y;
    size_t i = ((size_t)blockIdx.x * 256 + threadIdx.x) * 4;
    f32x4 v = *(const f32x4*)(src + l * sStride + i);
    u16x4 o;
    o.x = f2bf(v.x); o.y = f2bf(v.y); o.z = f2bf(v.z); o.w = f2bf(v.w);
    *(u16x4*)(dst + l * dStride + i) = o;
}

// f32 -> bf16 with row interleave: src row f -> dst row 2f+off (rows of D_)
__global__ __launch_bounds__(256)
void cvt_il_k(const float* __restrict__ src, u16* __restrict__ dst,
              unsigned long long sStride, unsigned long long dStride, int off)
{
    int f = blockIdx.x, l = blockIdx.y;
    int i = threadIdx.x * 4;
    f32x4 v = *(const f32x4*)(src + l * sStride + (size_t)f * D_ + i);
    u16x4 o;
    o.x = f2bf(v.x); o.y = f2bf(v.y); o.z = f2bf(v.z); o.w = f2bf(v.w);
    *(u16x4*)(dst + l * dStride + (size_t)(2 * f + off) * D_ + i) = o;
}

// ---------------------------------------------------------------------------
// FALLBACK GEMM (round-1, proven): cast-in-staging, multi-W split.
// ---------------------------------------------------------------------------
template<int BM, int BN, int EPI, int NW>
__global__ __launch_bounds__(256)
void gemm_k(const u16* __restrict__ A, int K,
            const float* __restrict__ W0, const float* __restrict__ W1p,
            const float* __restrict__ W2p, int N0, int N1, int N,
            float* __restrict__ Of, u16* __restrict__ Ob)
{
    constexpr int FM = BM / 32;
    constexpr int FN = BN / 32;
    constexpr int LS = 40;
    __shared__ u16 sA[BM * LS];
    __shared__ u16 sB[BN * LS];

    const int tid  = threadIdx.x;
    const int lane = tid & 63, wv = tid >> 6;
    const int wm = wv >> 1, wn = wv & 1;
    const int l15 = lane & 15, lhi = lane >> 4;
    const int m0 = wm * (BM / 2), n0 = wn * (BN / 2);
    const int tM = blockIdx.y, tN = blockIdx.x;

    f32x4 acc[FM][FN];
#pragma unroll
    for (int i = 0; i < FM; ++i)
#pragma unroll
        for (int j = 0; j < FN; ++j) acc[i][j] = f32x4{0.f, 0.f, 0.f, 0.f};

    for (int kt = 0; kt < K; kt += 32) {
#pragma unroll
        for (int i = 0; i < BM / 64; ++i) {
            int cid = tid + i * 256;
            int row = cid >> 2, kc = cid & 3;
            const u16* src = A + (size_t)(tM * BM + row) * K + kt + kc * 8;
            *(u32x4*)&sA[row * LS + kc * 8] = *(const u32x4*)src;
        }
#pragma unroll
        for (int i = 0; i < BN / 32; ++i) {
            int cid = tid + i * 256;
            int row = cid >> 3, kc = cid & 7;
            int n = tN * BN + row;
            const float* wr;
            if (NW == 1)      wr = W0 + (size_t)n * K;
            else if (NW == 2) wr = (n < N0) ? (W0 + (size_t)n * K)
                                            : (W1p + (size_t)(n - N0) * K);
            else              wr = (n < N0) ? (W0 + (size_t)n * K)
                               : (n < N0 + N1) ? (W1p + (size_t)(n - N0) * K)
                                               : (W2p + (size_t)(n - N0 - N1) * K);
            f32x4 v = *(const f32x4*)(wr + kt + kc * 4);
            u16x4 o;
            o.x = f2bf(v.x); o.y = f2bf(v.y); o.z = f2bf(v.z); o.w = f2bf(v.w);
            *(u16x4*)&sB[row * LS + kc * 4] = o;
        }
        __syncthreads();

        bf16x8 av[FM], bv[FN];
#pragma unroll
        for (int i = 0; i < FM; ++i)
            av[i] = *(const bf16x8*)&sA[(m0 + i * 16 + l15) * LS + lhi * 8];
#pragma unroll
        for (int j = 0; j < FN; ++j)
            bv[j] = *(const bf16x8*)&sB[(n0 + j * 16 + l15) * LS + lhi * 8];
#pragma unroll
        for (int i = 0; i < FM; ++i)
#pragma unroll
            for (int j = 0; j < FN; ++j)
                acc[i][j] = __builtin_amdgcn_mfma_f32_16x16x32_bf16(
                    av[i], bv[j], acc[i][j], 0, 0, 0);
        __syncthreads();
    }

#pragma unroll
    for (int i = 0; i < FM; ++i)
#pragma unroll
        for (int j = 0; j < FN; ++j) {
            size_t gm = (size_t)tM * BM + m0 + i * 16 + lhi * 4;
            size_t gn = (size_t)tN * BN + n0 + j * 16 + l15;
#pragma unroll
            for (int r = 0; r < 4; ++r) {
                float v = acc[i][j][r];
                size_t idx = (gm + r) * (size_t)N + gn;
                if (EPI == 0)      Ob[idx] = f2bf(v);
                else if (EPI == 1) Of[idx] = v;
                else               Of[idx] += v;
            }
        }
}

// ---------------------------------------------------------------------------
// V transpose: vt[(b*HK+hk)*DH + d][t] = V[b][t][hk][d]  (1 MB, L2-hot)
// ---------------------------------------------------------------------------
__global__ __launch_bounds__(256)
void vtrans_k(const u16* __restrict__ qkv, u16* __restrict__ vt)
{
    int rr = blockIdx.x;                  // 512 rows: (b*4+hk)*64 + d
    int d = rr & 63, hk = (rr >> 6) & 3, b = rr >> 8;
    int t = threadIdx.x * 4;
    const u16* base = qkv + (size_t)(b * T_ + t) * 1536 + 1280 + hk * 64 + d;
    u16 a0 = base[0];
    u16 a1 = base[1536];
    u16 a2 = base[3072];
    u16 a3 = base[4608];
    u16x4 o; o.x = a0; o.y = a1; o.z = a2; o.w = a3;
    *(u16x4*)(vt + (size_t)rr * T_ + t) = o;
}

// ---------------------------------------------------------------------------
// Flash attention v2 (causal, GQA G=4). Grid: (T/64, H, B).
// ---------------------------------------------------------------------------
__global__ __launch_bounds__(256)
void attn2_k(const u16* __restrict__ qkv, const u16* __restrict__ vt,
             u16* __restrict__ attn)
{
    const int qt = blockIdx.x, h = blockIdx.y, b = blockIdx.z;
    const int hk = h >> 2;
    const int tid = threadIdx.x;
    const int lane = tid & 63, w = tid >> 6;
    const int l15 = lane & 15, lhi = lane >> 4;

    __shared__ u16 sK[128 * 64];          // [kv][d], slot-swizzled
    __shared__ u16 sVT[64 * 128];         // [d][kv], slot-swizzled
    __shared__ u16 sP[4][16 * 136];       // per-wave P, padded stride

    const int q0 = qt * 64;
    const u16* qptr = qkv + (size_t)(b * T_ + q0 + w * 16 + l15) * 1536 + h * 64 + lhi * 8;
    bf16x8 aq0 = *(const bf16x8*)qptr;
    bf16x8 aq1 = *(const bf16x8*)(qptr + 32);

    f32x4 accO[4];
#pragma unroll
    for (int d = 0; d < 4; ++d) accO[d] = f32x4{0.f, 0.f, 0.f, 0.f};
    float m_r[4] = {-1e30f, -1e30f, -1e30f, -1e30f};
    float l_r[4] = {0.f, 0.f, 0.f, 0.f};
    const int myq = q0 + w * 16 + lhi * 4;
    const int qmaxw = q0 + w * 16 + 15;
    u16* sPw = sP[w];

    const int ntiles = (qt + 2) >> 1;
    const u16* vtb = vt + (size_t)((b * HK_ + hk) * DH_) * T_;
    const int L = lane;

    for (int kt = 0; kt < ntiles; ++kt) {
        const int t0 = kt * 128;
#pragma unroll
        for (int i = 0; i < 4; ++i) {
            int c = w * 4 + i;
            int row = c * 8 + (L >> 3);
            int p = L & 7;
            const u16* src = qkv + (size_t)(b * T_ + t0 + row) * 1536 + 1024 + hk * 64
                             + ((p ^ (row & 7)) * 8);
            gl_lds16(src, sK + c * 512);
        }
#pragma unroll
        for (int i = 0; i < 4; ++i) {
            int c = w * 4 + i;
            int row = c * 4 + (L >> 4);
            int p = L & 15;
            const u16* src = vtb + (size_t)row * T_ + t0 + ((p ^ (row & 15)) * 8);
            gl_lds16(src, sVT + c * 512);
        }
        asm volatile("s_waitcnt vmcnt(0)" ::: "memory");
        __syncthreads();

        const bool lastt = (kt == ntiles - 1);

        f32x4 accS[8];
#pragma unroll
        for (int nf = 0; nf < 8; ++nf)
            accS[nf] = f32x4{-1e30f, -1e30f, -1e30f, -1e30f};
#pragma unroll
        for (int pk = 0; pk < 4; ++pk) {
            if (t0 + pk * 32 > qmaxw) continue;
            f32x4 s0 = f32x4{0.f, 0.f, 0.f, 0.f};
            f32x4 s1 = f32x4{0.f, 0.f, 0.f, 0.f};
#pragma unroll
            for (int kk = 0; kk < 2; ++kk) {
                bf16x8 aqs = kk ? aq1 : aq0;
                int r0 = (pk * 2) * 16 + l15;
                int r1 = (pk * 2 + 1) * 16 + l15;
                int ls = kk * 4 + lhi;
                bf16x8 b0 = *(const bf16x8*)&sK[r0 * 64 + ((ls ^ (r0 & 7)) * 8)];
                bf16x8 b1 = *(const bf16x8*)&sK[r1 * 64 + ((ls ^ (r1 & 7)) * 8)];
                s0 = __builtin_amdgcn_mfma_f32_16x16x32_bf16(aqs, b0, s0, 0, 0, 0);
                s1 = __builtin_amdgcn_mfma_f32_16x16x32_bf16(aqs, b1, s1, 0, 0, 0);
            }
#pragma unroll
            for (int r = 0; r < 4; ++r) {
                float v0 = s0[r] * SCALE_;
                float v1 = s1[r] * SCALE_;
                if (lastt) {
                    int kp0 = t0 + (pk * 2) * 16 + l15;
                    int kp1 = kp0 + 16;
                    if (kp0 > myq + r) v0 = -1e30f;
                    if (kp1 > myq + r) v1 = -1e30f;
                }
                accS[pk * 2][r] = v0;
                accS[pk * 2 + 1][r] = v1;
            }
        }

        float sc[4];
#pragma unroll
        for (int r = 0; r < 4; ++r) {
            float mx = accS[0][r];
#pragma unroll
            for (int nf = 1; nf < 8; ++nf) mx = fmaxf(mx, accS[nf][r]);
#pragma unroll
            for (int off = 1; off < 16; off <<= 1) mx = fmaxf(mx, __shfl_xor(mx, off));
            float mn = fmaxf(m_r[r], mx);
            sc[r] = expf(m_r[r] - mn);
            m_r[r] = mn;
        }
        float rs[4] = {0.f, 0.f, 0.f, 0.f};
#pragma unroll
        for (int pk = 0; pk < 4; ++pk) {
            if (t0 + pk * 32 > qmaxw) continue;
#pragma unroll
            for (int g = 0; g < 2; ++g) {
                int nf = pk * 2 + g;
#pragma unroll
                for (int r = 0; r < 4; ++r) {
                    float p = expf(accS[nf][r] - m_r[r]);
                    accS[nf][r] = p;
                    rs[r] += p;
                }
            }
        }
#pragma unroll
        for (int r = 0; r < 4; ++r) {
#pragma unroll
            for (int off = 1; off < 16; off <<= 1) rs[r] += __shfl_xor(rs[r], off);
            l_r[r] = l_r[r] * sc[r] + rs[r];
        }
#pragma unroll
        for (int d = 0; d < 4; ++d)
#pragma unroll
            for (int r = 0; r < 4; ++r) accO[d][r] *= sc[r];

#pragma unroll
        for (int pk = 0; pk < 4; ++pk) {
            if (t0 + pk * 32 > qmaxw) continue;
#pragma unroll
            for (int g = 0; g < 2; ++g) {
                int nf = pk * 2 + g;
#pragma unroll
                for (int r = 0; r < 4; ++r)
                    sPw[(lhi * 4 + r) * 136 + nf * 16 + l15] = f2bf(accS[nf][r]);
            }
        }

#pragma unroll
        for (int kk = 0; kk < 4; ++kk) {
            if (t0 + kk * 32 > qmaxw) continue;
            bf16x8 pas = *(const bf16x8*)&sPw[l15 * 136 + kk * 32 + lhi * 8];
#pragma unroll
            for (int nf = 0; nf < 4; ++nf) {
                int row = nf * 16 + l15;
                int ls = kk * 4 + lhi;
                bf16x8 bvv = *(const bf16x8*)&sVT[row * 128 + ((ls ^ (row & 15)) * 8)];
                accO[nf] = __builtin_amdgcn_mfma_f32_16x16x32_bf16(pas, bvv, accO[nf], 0, 0, 0);
            }
        }
        __syncthreads();
    }

#pragma unroll
    for (int d = 0; d < 4; ++d)
#pragma unroll
        for (int r = 0; r < 4; ++r) {
            int row = q0 + w * 16 + lhi * 4 + r;
            float o = accO[d][r] / l_r[r];
            attn[(size_t)(b * T_ + row) * 1024 + h * 64 + d * 16 + l15] = f2bf(o);
        }
}

// ---------------------------------------------------------------------------
// FALLBACK attention (round-1 proven)
// ---------------------------------------------------------------------------
__global__ __launch_bounds__(256)
void attn_k(const u16* __restrict__ qkv, u16* __restrict__ attn)
{
    const int qt = blockIdx.x, h = blockIdx.y, b = blockIdx.z;
    const int hk = h >> 2;
    const int tid = threadIdx.x;
    const int lane = tid & 63, w = tid >> 6;
    const int l15 = lane & 15, lhi = lane >> 4;
    __shared__ u16 sK[64 * 72];
    __shared__ u16 sVT[64 * 74];
    __shared__ u16 sP[4 * 16 * 72];

    const int q0 = qt * 64;
    const u16* qptr = qkv + (size_t)(b * T_ + q0 + w * 16 + l15) * 1536 + h * 64 + lhi * 8;
    bf16x8 aq0 = *(const bf16x8*)qptr;
    bf16x8 aq1 = *(const bf16x8*)(qptr + 32);

    f32x4 accO[4];
#pragma unroll
    for (int d = 0; d < 4; ++d) accO[d] = f32x4{0.f, 0.f, 0.f, 0.f};
    float m_r[4] = {-1e30f, -1e30f, -1e30f, -1e30f};
    float l_r[4] = {0.f, 0.f, 0.f, 0.f};
    const int myq = q0 + w * 16 + lhi * 4;
    u16* sPw = sP + w * 16 * 72;

    for (int kt = 0; kt <= qt; ++kt) {
#pragma unroll
        for (int i = 0; i < 2; ++i) {
            int cid = tid + i * 256;
            int r = cid >> 3, kc = cid & 7;
            const u16* src = qkv + (size_t)(b * T_ + kt * 64 + r) * 1536 + 1024 + hk * 64 + kc * 8;
            *(u32x4*)&sK[r * 72 + kc * 8] = *(const u32x4*)src;
        }
#pragma unroll
        for (int i = 0; i < 2; ++i) {
            int cid = tid + i * 256;
            int tt = cid >> 3, dc = cid & 7;
            const u16* src = qkv + (size_t)(b * T_ + kt * 64 + tt) * 1536 + 1280 + hk * 64 + dc * 8;
            bf16x8 vv = *(const bf16x8*)src;
#pragma unroll
            for (int j = 0; j < 8; ++j) sVT[(dc * 8 + j) * 74 + tt] = (u16)vv[j];
        }
        __syncthreads();

        f32x4 accS[4];
#pragma unroll
        for (int nf = 0; nf < 4; ++nf) accS[nf] = f32x4{0.f, 0.f, 0.f, 0.f};
#pragma unroll
        for (int s = 0; s < 2; ++s) {
            bf16x8 aqs = s ? aq1 : aq0;
#pragma unroll
            for (int nf = 0; nf < 4; ++nf) {
                bf16x8 bk = *(const bf16x8*)&sK[(nf * 16 + l15) * 72 + s * 32 + lhi * 8];
                accS[nf] = __builtin_amdgcn_mfma_f32_16x16x32_bf16(aqs, bk, accS[nf], 0, 0, 0);
            }
        }
#pragma unroll
        for (int nf = 0; nf < 4; ++nf)
#pragma unroll
            for (int r = 0; r < 4; ++r) {
                float v = accS[nf][r] * SCALE_;
                if (kt == qt) {
                    int kp = kt * 64 + nf * 16 + l15;
                    if (kp > myq + r) v = -1e30f;
                }
                accS[nf][r] = v;
            }
        float sc[4];
#pragma unroll
        for (int r = 0; r < 4; ++r) {
            float mx = fmaxf(fmaxf(accS[0][r], accS[1][r]), fmaxf(accS[2][r], accS[3][r]));
#pragma unroll
            for (int off = 1; off < 16; off <<= 1) mx = fmaxf(mx, __shfl_xor(mx, off));
            float mn = fmaxf(m_r[r], mx);
            sc[r] = expf(m_r[r] - mn);
            m_r[r] = mn;
        }
        float rs[4] = {0.f, 0.f, 0.f, 0.f};
#pragma unroll
        for (int nf = 0; nf < 4; ++nf)
#pragma unroll
            for (int r = 0; r < 4; ++r) {
                float p = expf(accS[nf][r] - m_r[r]);
                accS[nf][r] = p;
                rs[r] += p;
            }
#pragma unroll
        for (int r = 0; r < 4; ++r) {
#pragma unroll
            for (int off = 1; off < 16; off <<= 1) rs[r] += __shfl_xor(rs[r], off);
            l_r[r] = l_r[r] * sc[r] + rs[r];
        }
#pragma unroll
        for (int d = 0; d < 4; ++d)
#pragma unroll
            for (int r = 0; r < 4; ++r) accO[d][r] *= sc[r];

#pragma unroll
        for (int nf = 0; nf < 4; ++nf)
#pragma unroll
            for (int r = 0; r < 4; ++r)
                sPw[(lhi * 4 + r) * 72 + nf * 16 + l15] = f2bf(accS[nf][r]);
        bf16x8 pa0 = *(const bf16x8*)&sPw[l15 * 72 + lhi * 8];
        bf16x8 pa1 = *(const bf16x8*)&sPw[l15 * 72 + 32 + lhi * 8];
#pragma unroll
        for (int s = 0; s < 2; ++s) {
            bf16x8 pas = s ? pa1 : pa0;
#pragma unroll
            for (int d = 0; d < 4; ++d) {
                bf16x8 bvv = *(const bf16x8*)&sVT[(d * 16 + l15) * 74 + s * 32 + lhi * 8];
                accO[d] = __builtin_amdgcn_mfma_f32_16x16x32_bf16(pas, bvv, accO[d], 0, 0, 0);
            }
        }
        __syncthreads();
    }

#pragma unroll
    for (int d = 0; d < 4; ++d)
#pragma unroll
        for (int r = 0; r < 4; ++r) {
            int row = q0 + w * 16 + lhi * 4 + r;
            float o = accO[d][r] / l_r[r];
            attn[(size_t)(b * T_ + row) * 1024 + h * 64 + d * 16 + l15] = f2bf(o);
        }
}

// ---------------------------------------------------------------------------
// Small elementwise kernels
// ---------------------------------------------------------------------------
__global__ __launch_bounds__(256)
void gather_k(const int* __restrict__ ids, const float* __restrict__ emb,
              float* __restrict__ x)
{
    int m = blockIdx.x, tid = threadIdx.x;
    int id = ids[m];
    *(f32x4*)(x + (size_t)m * D_ + tid * 4) =
        *(const f32x4*)(emb + (size_t)id * D_ + tid * 4);
}

__global__ __launch_bounds__(256)
void rmsnorm_k(const float* __restrict__ x, const float* __restrict__ g,
               u16* __restrict__ out)
{
    const int row = blockIdx.x, tid = threadIdx.x;
    const float* xr = x + (size_t)row * D_;
    f32x4 v = *(const f32x4*)(xr + tid * 4);
    float ss = v.x * v.x + v.y * v.y + v.z * v.z + v.w * v.w;
#pragma unroll
    for (int off = 32; off >= 1; off >>= 1) ss += __shfl_xor(ss, off);
    __shared__ float red[4];
    if ((tid & 63) == 0) red[tid >> 6] = ss;
    __syncthreads();
    float tot = red[0] + red[1] + red[2] + red[3];
    float rr = rsqrtf(tot * (1.0f / D_) + 1e-6f);
    f32x4 wv = *(const f32x4*)(g + tid * 4);
    u16x4 o;
    o.x = f2bf(v.x * rr * wv.x); o.y = f2bf(v.y * rr * wv.y);
    o.z = f2bf(v.z * rr * wv.z); o.w = f2bf(v.w * rr * wv.w);
    *(u16x4*)(out + (size_t)row * D_ + tid * 4) = o;
}

// cos/sin tables: tab[t*32 + j] = cos/sin(t * theta^(-j/32))
__global__ __launch_bounds__(256)
void rope_tab_k(float* __restrict__ tc, float* __restrict__ ts)
{
    int idx = blockIdx.x * 256 + threadIdx.x;
    int t = idx >> 5, j = idx & 31;
    float inv = powf(10000.0f, -(float)j * (1.0f / 32.0f));
    float ang = (float)t * inv;
    tc[idx] = cosf(ang);
    ts[idx] = sinf(ang);
}

// f32-silu (fallback path)
__global__ __launch_bounds__(256)
void silu_f32_k(const float* __restrict__ h13, u16* __restrict__ hh)
{
    int m = blockIdx.y;
    int f = blockIdx.x * 256 + threadIdx.x;
    float a = h13[(size_t)m * (2 * F_) + f];
    float c = h13[(size_t)m * (2 * F_) + F_ + f];
    float s = a / (1.0f + expf(-a));
    hh[(size_t)m * F_ + f] = f2bf(s * c);
}

__global__ __launch_bounds__(640)
void rope_slow_k(u16* __restrict__ qkv)
{
    int m = blockIdx.x;
    int c2 = threadIdx.x;
    int col = (c2 < 512) ? (c2 * 2) : (1024 + (c2 - 512) * 2);
    int d = col & 63;
    int t = m & (T_ - 1);
    float ang = (float)t * powf(10000.0f, -(float)d / 64.0f);
    float cs = cosf(ang), sn = sinf(ang);
    u16* p = qkv + (size_t)m * 1536 + col;
    float x0 = bf2f(p[0]), x1 = bf2f(p[1]);
    p[0] = f2bf(x0 * cs - x1 * sn);
    p[1] = f2bf(x0 * sn + x1 * cs);
}

// ---------------------------------------------------------------------------
extern "C" void kernel_launch(void* const* d_in, const int* in_sizes, int n_in,
                              void* d_out, int out_size, void* d_ws, size_t ws_size,
                              hipStream_t stream)
{
    const int*   ids = (const int*)d_in[0];
    const float* emb = (const float*)d_in[1];
    const float* qw  = (const float*)d_in[2];
    const float* kw  = (const float*)d_in[3];
    const float* vw  = (const float*)d_in[4];
    const float* ow  = (const float*)d_in[5];
    const float* w1  = (const float*)d_in[6];
    const float* w2  = (const float*)d_in[7];
    const float* w3  = (const float*)d_in[8];
    const float* n1  = (const float*)d_in[9];
    const float* n2  = (const float*)d_in[10];
    const float* nfw = (const float*)d_in[11];
    float* out = (float*)d_out;
    char*  ws  = (char*)d_ws;

    // ---- workspace layout ----
    float* x    = (float*)(ws);                    //  8 MB residual f32
    u16*   xn   = (u16*)(ws + 8388608ULL);         //  4 MB normed acts
    u16*   qkvb = (u16*)(ws + 12582912ULL);        //  6 MB fused qkv
    u16*   attnb= (u16*)(ws + 18874368ULL);        //  4 MB attn out
    u16*   hh   = (u16*)(ws + 46137344ULL);        // 11 MB silu(h1)*h3
    float* ropec= (float*)(ws + 57671680ULL);      // 128 KB
    float* ropes= (float*)(ws + 57802752ULL);      // 128 KB
    u16*   embb = (u16*)(ws + 57933824ULL);        // 62.5 MB
    u16*   wqkv = (u16*)(ws + 123469824ULL);       // 24 MB
    u16*   wob  = (u16*)(ws + 148635648ULL);       // 16 MB
    u16*   w13b = (u16*)(ws + 165412864ULL);       // 88 MB (w1/w3 row-interleaved)
    u16*   w2b  = (u16*)(ws + 257687552ULL);       // 44 MB
    u16*   vtb  = (u16*)(ws + 303824896ULL);       //  1 MB V^T scratch
    const unsigned long long NEED = 304873472ULL;

    if (ws_size >= NEED) {
        cvt_k<<<dim3(32000, 1), 256, 0, stream>>>(emb, embb, 0, 0);
        cvt_k<<<dim3(1024, L_), 256, 0, stream>>>(qw, wqkv,            1048576ULL, 1572864ULL);
        cvt_k<<<dim3(256,  L_), 256, 0, stream>>>(kw, wqkv + 1048576,  262144ULL,  1572864ULL);
        cvt_k<<<dim3(256,  L_), 256, 0, stream>>>(vw, wqkv + 1310720,  262144ULL,  1572864ULL);
        cvt_k<<<dim3(1024, L_), 256, 0, stream>>>(ow, wob,             1048576ULL, 1048576ULL);
        cvt_il_k<<<dim3(2816, L_), 256, 0, stream>>>(w1, w13b, 2883584ULL, 5767168ULL, 0);
        cvt_il_k<<<dim3(2816, L_), 256, 0, stream>>>(w3, w13b, 2883584ULL, 5767168ULL, 1);
        cvt_k<<<dim3(2816, L_), 256, 0, stream>>>(w2, w2b,             2883584ULL, 2883584ULL);
        rope_tab_k<<<T_ * 32 / 256, 256, 0, stream>>>(ropec, ropes);

        gather_k<<<M_, 256, 0, stream>>>(ids, emb, x);

        for (int l = 0; l < L_; ++l) {
            rmsnorm_k<<<M_, 256, 0, stream>>>(x, n1 + l * D_, xn);
            // fused QKV + RoPE
            gemm3_k<64, 4><<<32 * 12, 256, 0, stream>>>(
                xn, D_, wqkv + (size_t)l * 1572864, 1536, nullptr, qkvb, ropec, ropes);
            vtrans_k<<<B_ * HK_ * DH_, 256, 0, stream>>>(qkvb, vtb);
            attn2_k<<<dim3(T_ / 64, H_, B_), 256, 0, stream>>>(qkvb, vtb, attnb);
            gemm3_k<64, 2><<<32 * 8, 256, 0, stream>>>(
                attnb, D_, wob + (size_t)l * 1048576, 1024, x, nullptr, nullptr, nullptr);
            rmsnorm_k<<<M_, 256, 0, stream>>>(x, n2 + l * D_, xn);
            // fused W1||W3 (interleaved) + SiLU -> hh
            gemm3_k<128, 3><<<16 * 44, 256, 0, stream>>>(
                xn, D_, w13b + (size_t)l * 5767168, 5632, nullptr, hh, nullptr, nullptr);
            gemm3_k<64, 2><<<32 * 8, 256, 0, stream>>>(
                hh, F_, w2b + (size_t)l * 2883584, 1024, x, nullptr, nullptr, nullptr);
        }

        rmsnorm_k<<<M_, 256, 0, stream>>>(x, nfw, xn);
        gemm3_k<128, 1><<<16 * 250, 256, 0, stream>>>(
            xn, D_, embb, V_, out, nullptr, nullptr, nullptr);
        return;
    }

    // ---------------- fallback: round-1 proven path ----------------
    float* h13f = (float*)(ws + 23068672ULL);
    u16*   hhf  = (u16*)(ws + 69206016ULL);
    gather_k<<<M_, 256, 0, stream>>>(ids, emb, x);

    for (int l = 0; l < L_; ++l) {
        rmsnorm_k<<<M_, 256, 0, stream>>>(x, n1 + l * D_, xn);
        gemm_k<128, 64, 0, 3><<<dim3(24, 16), 256, 0, stream>>>(
            xn, D_,
            qw + (size_t)l * H_ * DH_ * D_,
            kw + (size_t)l * HK_ * DH_ * D_,
            vw + (size_t)l * HK_ * DH_ * D_,
            1024, 256, 1536, nullptr, qkvb);
        rope_slow_k<<<M_, 640, 0, stream>>>(qkvb);
        attn_k<<<dim3(T_ / 64, H_, B_), 256, 0, stream>>>(qkvb, attnb);
        gemm_k<128, 64, 2, 1><<<dim3(16, 16), 256, 0, stream>>>(
            attnb, D_, ow + (size_t)l * D_ * D_, nullptr, nullptr,
            0, 0, D_, x, nullptr);
        rmsnorm_k<<<M_, 256, 0, stream>>>(x, n2 + l * D_, xn);
        gemm_k<128, 128, 1, 2><<<dim3(44, 16), 256, 0, stream>>>(
            xn, D_, w1 + (size_t)l * F_ * D_, w3 + (size_t)l * F_ * D_, nullptr,
            F_, 0, 2 * F_, h13f, nullptr);
        silu_f32_k<<<dim3(11, M_), 256, 0, stream>>>(h13f, hhf);
        gemm_k<128, 64, 2, 1><<<dim3(16, 16), 256, 0, stream>>>(
            hhf, F_, w2 + (size_t)l * D_ * F_, nullptr, nullptr,
            0, 0, D_, x, nullptr);
    }

    rmsnorm_k<<<M_, 256, 0, stream>>>(x, nfw, xn);
    gemm_k<128, 128, 1, 1><<<dim3(250, 16), 256, 0, stream>>>(
        xn, D_, emb, nullptr, nullptr, 0, 0, V_, out, nullptr);
}

// Round 7
// 1824.692 us; speedup vs baseline: 1.1096x; 1.1096x over previous
//
#include <hip/hip_runtime.h>
#include <math.h>

#define L_ 8
#define D_ 1024
#define H_ 16
#define HK_ 4
#define DH_ 64
#define F_ 2816
#define V_ 32000
#define T_ 1024
#define B_ 2
#define M_ (B_*T_)          // 2048 tokens
#define SCALE_ 0.125f       // DH^-0.5

typedef unsigned short u16;
typedef unsigned int   u32;
typedef __attribute__((ext_vector_type(4))) float  f32x4;
typedef __attribute__((ext_vector_type(8))) short  bf16x8;   // 8 bf16 = 4 VGPRs (MFMA A/B frag)
typedef __attribute__((ext_vector_type(4))) unsigned short u16x4;
typedef __attribute__((ext_vector_type(4))) unsigned int   u32x4;

__device__ __forceinline__ float bf2f(u16 h) {
    union { u32 u; float f; } v; v.u = ((u32)h) << 16; return v.f;
}
__device__ __forceinline__ u16 f2bf(float f) {   // round-to-nearest-even
    union { float f; u32 u; } v; v.f = f;
    u32 r = v.u + 0x7fffu + ((v.u >> 16) & 1u);
    return (u16)(r >> 16);
}

__device__ __forceinline__ void gl_lds16(const void* g, void* l) {
    __builtin_amdgcn_global_load_lds(
        (const __attribute__((address_space(1))) unsigned int*)g,
        (__attribute__((address_space(3))) unsigned int*)l,
        16, 0, 0);
}

// ---------------------------------------------------------------------------
// 2-phase double-buffered GEMM (proven round-5 structure): C[M,N]=A[M,K] x
// W[N,K]^T, bf16. BK=32, 4 waves 2x2, bijective XCD swizzle, global_load_lds.
// EPI: 0 = bf16 store, 1 = f32 store, 2 = f32 +=,
//      3 = fused SiLU (w1/w3 row-interleaved; even col=h1, odd=h3 -> Ob[M][F_])
//      4 = fused RoPE (cols<1280 rotated; v cols 1280..1536 -> vt (via Of))
// ---------------------------------------------------------------------------
template<int BM, int BN, int EPI>
__global__ __launch_bounds__(256)
void gemm2_k(const u16* __restrict__ A, int K,
             const u16* __restrict__ W, int N,
             float* __restrict__ Of, u16* __restrict__ Ob,
             const float* __restrict__ tc, const float* __restrict__ ts)
{
    constexpr int FM = BM / 32;
    constexpr int FN = BN / 32;
    constexpr int GM = M_ / BM;
    constexpr int IPA = BM / 64;
    constexpr int IPB = BN / 64;
    __shared__ u16 sA[2 * BM * 32];
    __shared__ u16 sB[2 * BN * 32];

    const int tid  = threadIdx.x;
    const int lane = tid & 63, wv = tid >> 6;
    const int wm = wv >> 1, wn = wv & 1;
    const int l15 = lane & 15, lhi = lane >> 4;
    const int m0 = wm * (BM / 2), n0 = wn * (BN / 2);

    const int nwg = gridDim.x;
    const int q8 = nwg >> 3, r8 = nwg & 7;
    const int xcd = blockIdx.x & 7, off8 = blockIdx.x >> 3;
    const int wgid = (xcd < r8 ? xcd * (q8 + 1) : r8 * (q8 + 1) + (xcd - r8) * q8) + off8;
    const int tM = wgid % GM, tN = wgid / GM;

    const int srow = lane >> 2;
    const int scol = (lane & 3) * 8;

    const u16* Abase = A + (size_t)(tM * BM) * K;
    const u16* Wbase = W + (size_t)(tN * BN) * K;

    f32x4 acc[FM][FN];
#pragma unroll
    for (int i = 0; i < FM; ++i)
#pragma unroll
        for (int j = 0; j < FN; ++j) acc[i][j] = f32x4{0.f, 0.f, 0.f, 0.f};

    auto stage = [&](int kt, int buf) {
        u16* sa = sA + buf * (BM * 32);
        u16* sb = sB + buf * (BN * 32);
#pragma unroll
        for (int i = 0; i < IPA; ++i) {
            int c = wv * IPA + i;
            gl_lds16(Abase + (size_t)(c * 16 + srow) * K + kt + scol, sa + c * 512);
        }
#pragma unroll
        for (int i = 0; i < IPB; ++i) {
            int c = wv * IPB + i;
            gl_lds16(Wbase + (size_t)(c * 16 + srow) * K + kt + scol, sb + c * 512);
        }
    };

    const int nt = K >> 5;
    stage(0, 0);
    asm volatile("s_waitcnt vmcnt(0)" ::: "memory");
    __syncthreads();

    int cur = 0;
    for (int t = 0; t < nt; ++t) {
        if (t + 1 < nt) stage((t + 1) << 5, cur ^ 1);

        const u16* sa = sA + cur * (BM * 32);
        const u16* sb = sB + cur * (BN * 32);
        bf16x8 av[FM], bv[FN];
#pragma unroll
        for (int i = 0; i < FM; ++i)
            av[i] = *(const bf16x8*)&sa[(m0 + i * 16 + l15) * 32 + lhi * 8];
#pragma unroll
        for (int j = 0; j < FN; ++j)
            bv[j] = *(const bf16x8*)&sb[(n0 + j * 16 + l15) * 32 + lhi * 8];
#pragma unroll
        for (int i = 0; i < FM; ++i)
#pragma unroll
            for (int j = 0; j < FN; ++j)
                acc[i][j] = __builtin_amdgcn_mfma_f32_16x16x32_bf16(
                    av[i], bv[j], acc[i][j], 0, 0, 0);

        if (t + 1 < nt) {
            asm volatile("s_waitcnt vmcnt(0)" ::: "memory");
            __syncthreads();
            cur ^= 1;
        }
    }

    // epilogue: D col = lane&15, row = (lane>>4)*4 + reg
#pragma unroll
    for (int i = 0; i < FM; ++i)
#pragma unroll
        for (int j = 0; j < FN; ++j) {
            size_t gm = (size_t)tM * BM + m0 + i * 16 + lhi * 4;
            size_t gn = (size_t)tN * BN + n0 + j * 16 + l15;
#pragma unroll
            for (int r = 0; r < 4; ++r) {
                float v = acc[i][j][r];
                size_t idx = (gm + r) * (size_t)N + gn;
                if (EPI == 0) {
                    Ob[idx] = f2bf(v);
                } else if (EPI == 1) {
                    Of[idx] = v;
                } else if (EPI == 2) {
                    Of[idx] += v;
                } else if (EPI == 3) {
                    float b = __shfl_xor(v, 1);
                    if ((lane & 1) == 0) {
                        float s = v / (1.0f + expf(-v));
                        Ob[(gm + r) * (size_t)F_ + (gn >> 1)] = f2bf(s * b);
                    }
                } else {   // EPI == 4: RoPE q/k; v cols -> transposed vt
                    float b = __shfl_xor(v, 1);
                    int gni = (int)gn;
                    int gmr = (int)(gm + r);
                    if (gni < 1280) {
                        int dd = gni & 63;
                        int jj = dd >> 1;
                        int tt = gmr & (T_ - 1);
                        float c = tc[tt * 32 + jj], s = ts[tt * 32 + jj];
                        float ro = ((dd & 1) == 0) ? (v * c - b * s) : (b * s + v * c);
                        Ob[idx] = f2bf(ro);
                    } else {
                        int vc = gni - 1280;              // 0..255
                        int hk = vc >> 6, dd = vc & 63;
                        int bb = gmr >> 10, tt = gmr & (T_ - 1);
                        ((u16*)Of)[((size_t)((bb * HK_ + hk) * DH_ + dd)) * T_ + tt] = f2bf(v);
                    }
                }
            }
        }
}

// f32 -> bf16 layer-strided conversion
__global__ __launch_bounds__(256)
void cvt_k(const float* __restrict__ src, u16* __restrict__ dst,
           unsigned long long sStride, unsigned long long dStride)
{
    int l = blockIdx.y;
    size_t i = ((size_t)blockIdx.x * 256 + threadIdx.x) * 4;
    f32x4 v = *(const f32x4*)(src + l * sStride + i);
    u16x4 o;
    o.x = f2bf(v.x); o.y = f2bf(v.y); o.z = f2bf(v.z); o.w = f2bf(v.w);
    *(u16x4*)(dst + l * dStride + i) = o;
}

// f32 -> bf16 with row interleave: src row f -> dst row 2f+off (rows of D_)
__global__ __launch_bounds__(256)
void cvt_il_k(const float* __restrict__ src, u16* __restrict__ dst,
              unsigned long long sStride, unsigned long long dStride, int off)
{
    int f = blockIdx.x, l = blockIdx.y;
    int i = threadIdx.x * 4;
    f32x4 v = *(const f32x4*)(src + l * sStride + (size_t)f * D_ + i);
    u16x4 o;
    o.x = f2bf(v.x); o.y = f2bf(v.y); o.z = f2bf(v.z); o.w = f2bf(v.w);
    *(u16x4*)(dst + l * dStride + (size_t)(2 * f + off) * D_ + i) = o;
}

// ---------------------------------------------------------------------------
// FALLBACK GEMM (round-1, proven): cast-in-staging, multi-W split.
// ---------------------------------------------------------------------------
template<int BM, int BN, int EPI, int NW>
__global__ __launch_bounds__(256)
void gemm_k(const u16* __restrict__ A, int K,
            const float* __restrict__ W0, const float* __restrict__ W1p,
            const float* __restrict__ W2p, int N0, int N1, int N,
            float* __restrict__ Of, u16* __restrict__ Ob)
{
    constexpr int FM = BM / 32;
    constexpr int FN = BN / 32;
    constexpr int LS = 40;
    __shared__ u16 sA[BM * LS];
    __shared__ u16 sB[BN * LS];

    const int tid  = threadIdx.x;
    const int lane = tid & 63, wv = tid >> 6;
    const int wm = wv >> 1, wn = wv & 1;
    const int l15 = lane & 15, lhi = lane >> 4;
    const int m0 = wm * (BM / 2), n0 = wn * (BN / 2);
    const int tM = blockIdx.y, tN = blockIdx.x;

    f32x4 acc[FM][FN];
#pragma unroll
    for (int i = 0; i < FM; ++i)
#pragma unroll
        for (int j = 0; j < FN; ++j) acc[i][j] = f32x4{0.f, 0.f, 0.f, 0.f};

    for (int kt = 0; kt < K; kt += 32) {
#pragma unroll
        for (int i = 0; i < BM / 64; ++i) {
            int cid = tid + i * 256;
            int row = cid >> 2, kc = cid & 3;
            const u16* src = A + (size_t)(tM * BM + row) * K + kt + kc * 8;
            *(u32x4*)&sA[row * LS + kc * 8] = *(const u32x4*)src;
        }
#pragma unroll
        for (int i = 0; i < BN / 32; ++i) {
            int cid = tid + i * 256;
            int row = cid >> 3, kc = cid & 7;
            int n = tN * BN + row;
            const float* wr;
            if (NW == 1)      wr = W0 + (size_t)n * K;
            else if (NW == 2) wr = (n < N0) ? (W0 + (size_t)n * K)
                                            : (W1p + (size_t)(n - N0) * K);
            else              wr = (n < N0) ? (W0 + (size_t)n * K)
                               : (n < N0 + N1) ? (W1p + (size_t)(n - N0) * K)
                                               : (W2p + (size_t)(n - N0 - N1) * K);
            f32x4 v = *(const f32x4*)(wr + kt + kc * 4);
            u16x4 o;
            o.x = f2bf(v.x); o.y = f2bf(v.y); o.z = f2bf(v.z); o.w = f2bf(v.w);
            *(u16x4*)&sB[row * LS + kc * 4] = o;
        }
        __syncthreads();

        bf16x8 av[FM], bv[FN];
#pragma unroll
        for (int i = 0; i < FM; ++i)
            av[i] = *(const bf16x8*)&sA[(m0 + i * 16 + l15) * LS + lhi * 8];
#pragma unroll
        for (int j = 0; j < FN; ++j)
            bv[j] = *(const bf16x8*)&sB[(n0 + j * 16 + l15) * LS + lhi * 8];
#pragma unroll
        for (int i = 0; i < FM; ++i)
#pragma unroll
            for (int j = 0; j < FN; ++j)
                acc[i][j] = __builtin_amdgcn_mfma_f32_16x16x32_bf16(
                    av[i], bv[j], acc[i][j], 0, 0, 0);
        __syncthreads();
    }

#pragma unroll
    for (int i = 0; i < FM; ++i)
#pragma unroll
        for (int j = 0; j < FN; ++j) {
            size_t gm = (size_t)tM * BM + m0 + i * 16 + lhi * 4;
            size_t gn = (size_t)tN * BN + n0 + j * 16 + l15;
#pragma unroll
            for (int r = 0; r < 4; ++r) {
                float v = acc[i][j][r];
                size_t idx = (gm + r) * (size_t)N + gn;
                if (EPI == 0)      Ob[idx] = f2bf(v);
                else if (EPI == 1) Of[idx] = v;
                else               Of[idx] += v;
            }
        }
}

// ---------------------------------------------------------------------------
// Flash attention v2 (causal, GQA G=4). Grid: (T/64, H, B). qt reversed so
// longest blocks dispatch first (load balance).
// ---------------------------------------------------------------------------
__global__ __launch_bounds__(256)
void attn2_k(const u16* __restrict__ qkv, const u16* __restrict__ vt,
             u16* __restrict__ attn)
{
    const int qt = gridDim.x - 1 - blockIdx.x;   // long blocks first
    const int h = blockIdx.y, b = blockIdx.z;
    const int hk = h >> 2;
    const int tid = threadIdx.x;
    const int lane = tid & 63, w = tid >> 6;
    const int l15 = lane & 15, lhi = lane >> 4;

    __shared__ u16 sK[128 * 64];          // [kv][d], slot-swizzled
    __shared__ u16 sVT[64 * 128];         // [d][kv], slot-swizzled
    __shared__ u16 sP[4][16 * 136];       // per-wave P, padded stride

    const int q0 = qt * 64;
    const u16* qptr = qkv + (size_t)(b * T_ + q0 + w * 16 + l15) * 1536 + h * 64 + lhi * 8;
    bf16x8 aq0 = *(const bf16x8*)qptr;
    bf16x8 aq1 = *(const bf16x8*)(qptr + 32);

    f32x4 accO[4];
#pragma unroll
    for (int d = 0; d < 4; ++d) accO[d] = f32x4{0.f, 0.f, 0.f, 0.f};
    float m_r[4] = {-1e30f, -1e30f, -1e30f, -1e30f};
    float l_r[4] = {0.f, 0.f, 0.f, 0.f};
    const int myq = q0 + w * 16 + lhi * 4;
    const int qmaxw = q0 + w * 16 + 15;
    u16* sPw = sP[w];

    const int ntiles = (qt + 2) >> 1;
    const u16* vtb = vt + (size_t)((b * HK_ + hk) * DH_) * T_;
    const int L = lane;

    for (int kt = 0; kt < ntiles; ++kt) {
        const int t0 = kt * 128;
#pragma unroll
        for (int i = 0; i < 4; ++i) {
            int c = w * 4 + i;
            int row = c * 8 + (L >> 3);
            int p = L & 7;
            const u16* src = qkv + (size_t)(b * T_ + t0 + row) * 1536 + 1024 + hk * 64
                             + ((p ^ (row & 7)) * 8);
            gl_lds16(src, sK + c * 512);
        }
#pragma unroll
        for (int i = 0; i < 4; ++i) {
            int c = w * 4 + i;
            int row = c * 4 + (L >> 4);
            int p = L & 15;
            const u16* src = vtb + (size_t)row * T_ + t0 + ((p ^ (row & 15)) * 8);
            gl_lds16(src, sVT + c * 512);
        }
        asm volatile("s_waitcnt vmcnt(0)" ::: "memory");
        __syncthreads();

        const bool lastt = (kt == ntiles - 1);

        f32x4 accS[8];
#pragma unroll
        for (int nf = 0; nf < 8; ++nf)
            accS[nf] = f32x4{-1e30f, -1e30f, -1e30f, -1e30f};
#pragma unroll
        for (int pk = 0; pk < 4; ++pk) {
            if (t0 + pk * 32 > qmaxw) continue;
            f32x4 s0 = f32x4{0.f, 0.f, 0.f, 0.f};
            f32x4 s1 = f32x4{0.f, 0.f, 0.f, 0.f};
#pragma unroll
            for (int kk = 0; kk < 2; ++kk) {
                bf16x8 aqs = kk ? aq1 : aq0;
                int r0 = (pk * 2) * 16 + l15;
                int r1 = (pk * 2 + 1) * 16 + l15;
                int ls = kk * 4 + lhi;
                bf16x8 b0 = *(const bf16x8*)&sK[r0 * 64 + ((ls ^ (r0 & 7)) * 8)];
                bf16x8 b1 = *(const bf16x8*)&sK[r1 * 64 + ((ls ^ (r1 & 7)) * 8)];
                s0 = __builtin_amdgcn_mfma_f32_16x16x32_bf16(aqs, b0, s0, 0, 0, 0);
                s1 = __builtin_amdgcn_mfma_f32_16x16x32_bf16(aqs, b1, s1, 0, 0, 0);
            }
#pragma unroll
            for (int r = 0; r < 4; ++r) {
                float v0 = s0[r] * SCALE_;
                float v1 = s1[r] * SCALE_;
                if (lastt) {
                    int kp0 = t0 + (pk * 2) * 16 + l15;
                    int kp1 = kp0 + 16;
                    if (kp0 > myq + r) v0 = -1e30f;
                    if (kp1 > myq + r) v1 = -1e30f;
                }
                accS[pk * 2][r] = v0;
                accS[pk * 2 + 1][r] = v1;
            }
        }

        float sc[4];
#pragma unroll
        for (int r = 0; r < 4; ++r) {
            float mx = accS[0][r];
#pragma unroll
            for (int nf = 1; nf < 8; ++nf) mx = fmaxf(mx, accS[nf][r]);
#pragma unroll
            for (int off = 1; off < 16; off <<= 1) mx = fmaxf(mx, __shfl_xor(mx, off));
            float mn = fmaxf(m_r[r], mx);
            sc[r] = expf(m_r[r] - mn);
            m_r[r] = mn;
        }
        float rs[4] = {0.f, 0.f, 0.f, 0.f};
#pragma unroll
        for (int pk = 0; pk < 4; ++pk) {
            if (t0 + pk * 32 > qmaxw) continue;
#pragma unroll
            for (int g = 0; g < 2; ++g) {
                int nf = pk * 2 + g;
#pragma unroll
                for (int r = 0; r < 4; ++r) {
                    float p = expf(accS[nf][r] - m_r[r]);
                    accS[nf][r] = p;
                    rs[r] += p;
                }
            }
        }
#pragma unroll
        for (int r = 0; r < 4; ++r) {
#pragma unroll
            for (int off = 1; off < 16; off <<= 1) rs[r] += __shfl_xor(rs[r], off);
            l_r[r] = l_r[r] * sc[r] + rs[r];
        }
#pragma unroll
        for (int d = 0; d < 4; ++d)
#pragma unroll
            for (int r = 0; r < 4; ++r) accO[d][r] *= sc[r];

#pragma unroll
        for (int pk = 0; pk < 4; ++pk) {
            if (t0 + pk * 32 > qmaxw) continue;
#pragma unroll
            for (int g = 0; g < 2; ++g) {
                int nf = pk * 2 + g;
#pragma unroll
                for (int r = 0; r < 4; ++r)
                    sPw[(lhi * 4 + r) * 136 + nf * 16 + l15] = f2bf(accS[nf][r]);
            }
        }

#pragma unroll
        for (int kk = 0; kk < 4; ++kk) {
            if (t0 + kk * 32 > qmaxw) continue;
            bf16x8 pas = *(const bf16x8*)&sPw[l15 * 136 + kk * 32 + lhi * 8];
#pragma unroll
            for (int nf = 0; nf < 4; ++nf) {
                int row = nf * 16 + l15;
                int ls = kk * 4 + lhi;
                bf16x8 bvv = *(const bf16x8*)&sVT[row * 128 + ((ls ^ (row & 15)) * 8)];
                accO[nf] = __builtin_amdgcn_mfma_f32_16x16x32_bf16(pas, bvv, accO[nf], 0, 0, 0);
            }
        }
        __syncthreads();
    }

#pragma unroll
    for (int d = 0; d < 4; ++d)
#pragma unroll
        for (int r = 0; r < 4; ++r) {
            int row = q0 + w * 16 + lhi * 4 + r;
            float o = accO[d][r] / l_r[r];
            attn[(size_t)(b * T_ + row) * 1024 + h * 64 + d * 16 + l15] = f2bf(o);
        }
}

// ---------------------------------------------------------------------------
// FALLBACK attention (round-1 proven)
// ---------------------------------------------------------------------------
__global__ __launch_bounds__(256)
void attn_k(const u16* __restrict__ qkv, u16* __restrict__ attn)
{
    const int qt = blockIdx.x, h = blockIdx.y, b = blockIdx.z;
    const int hk = h >> 2;
    const int tid = threadIdx.x;
    const int lane = tid & 63, w = tid >> 6;
    const int l15 = lane & 15, lhi = lane >> 4;
    __shared__ u16 sK[64 * 72];
    __shared__ u16 sVT[64 * 74];
    __shared__ u16 sP[4 * 16 * 72];

    const int q0 = qt * 64;
    const u16* qptr = qkv + (size_t)(b * T_ + q0 + w * 16 + l15) * 1536 + h * 64 + lhi * 8;
    bf16x8 aq0 = *(const bf16x8*)qptr;
    bf16x8 aq1 = *(const bf16x8*)(qptr + 32);

    f32x4 accO[4];
#pragma unroll
    for (int d = 0; d < 4; ++d) accO[d] = f32x4{0.f, 0.f, 0.f, 0.f};
    float m_r[4] = {-1e30f, -1e30f, -1e30f, -1e30f};
    float l_r[4] = {0.f, 0.f, 0.f, 0.f};
    const int myq = q0 + w * 16 + lhi * 4;
    u16* sPw = sP + w * 16 * 72;

    for (int kt = 0; kt <= qt; ++kt) {
#pragma unroll
        for (int i = 0; i < 2; ++i) {
            int cid = tid + i * 256;
            int r = cid >> 3, kc = cid & 7;
            const u16* src = qkv + (size_t)(b * T_ + kt * 64 + r) * 1536 + 1024 + hk * 64 + kc * 8;
            *(u32x4*)&sK[r * 72 + kc * 8] = *(const u32x4*)src;
        }
#pragma unroll
        for (int i = 0; i < 2; ++i) {
            int cid = tid + i * 256;
            int tt = cid >> 3, dc = cid & 7;
            const u16* src = qkv + (size_t)(b * T_ + kt * 64 + tt) * 1536 + 1280 + hk * 64 + dc * 8;
            bf16x8 vv = *(const bf16x8*)src;
#pragma unroll
            for (int j = 0; j < 8; ++j) sVT[(dc * 8 + j) * 74 + tt] = (u16)vv[j];
        }
        __syncthreads();

        f32x4 accS[4];
#pragma unroll
        for (int nf = 0; nf < 4; ++nf) accS[nf] = f32x4{0.f, 0.f, 0.f, 0.f};
#pragma unroll
        for (int s = 0; s < 2; ++s) {
            bf16x8 aqs = s ? aq1 : aq0;
#pragma unroll
            for (int nf = 0; nf < 4; ++nf) {
                bf16x8 bk = *(const bf16x8*)&sK[(nf * 16 + l15) * 72 + s * 32 + lhi * 8];
                accS[nf] = __builtin_amdgcn_mfma_f32_16x16x32_bf16(aqs, bk, accS[nf], 0, 0, 0);
            }
        }
#pragma unroll
        for (int nf = 0; nf < 4; ++nf)
#pragma unroll
            for (int r = 0; r < 4; ++r) {
                float v = accS[nf][r] * SCALE_;
                if (kt == qt) {
                    int kp = kt * 64 + nf * 16 + l15;
                    if (kp > myq + r) v = -1e30f;
                }
                accS[nf][r] = v;
            }
        float sc[4];
#pragma unroll
        for (int r = 0; r < 4; ++r) {
            float mx = fmaxf(fmaxf(accS[0][r], accS[1][r]), fmaxf(accS[2][r], accS[3][r]));
#pragma unroll
            for (int off = 1; off < 16; off <<= 1) mx = fmaxf(mx, __shfl_xor(mx, off));
            float mn = fmaxf(m_r[r], mx);
            sc[r] = expf(m_r[r] - mn);
            m_r[r] = mn;
        }
        float rs[4] = {0.f, 0.f, 0.f, 0.f};
#pragma unroll
        for (int nf = 0; nf < 4; ++nf)
#pragma unroll
            for (int r = 0; r < 4; ++r) {
                float p = expf(accS[nf][r] - m_r[r]);
                accS[nf][r] = p;
                rs[r] += p;
            }
#pragma unroll
        for (int r = 0; r < 4; ++r) {
#pragma unroll
            for (int off = 1; off < 16; off <<= 1) rs[r] += __shfl_xor(rs[r], off);
            l_r[r] = l_r[r] * sc[r] + rs[r];
        }
#pragma unroll
        for (int d = 0; d < 4; ++d)
#pragma unroll
            for (int r = 0; r < 4; ++r) accO[d][r] *= sc[r];

#pragma unroll
        for (int nf = 0; nf < 4; ++nf)
#pragma unroll
            for (int r = 0; r < 4; ++r)
                sPw[(lhi * 4 + r) * 72 + nf * 16 + l15] = f2bf(accS[nf][r]);
        bf16x8 pa0 = *(const bf16x8*)&sPw[l15 * 72 + lhi * 8];
        bf16x8 pa1 = *(const bf16x8*)&sPw[l15 * 72 + 32 + lhi * 8];
#pragma unroll
        for (int s = 0; s < 2; ++s) {
            bf16x8 pas = s ? pa1 : pa0;
#pragma unroll
            for (int d = 0; d < 4; ++d) {
                bf16x8 bvv = *(const bf16x8*)&sVT[(d * 16 + l15) * 74 + s * 32 + lhi * 8];
                accO[d] = __builtin_amdgcn_mfma_f32_16x16x32_bf16(pas, bvv, accO[d], 0, 0, 0);
            }
        }
        __syncthreads();
    }

#pragma unroll
    for (int d = 0; d < 4; ++d)
#pragma unroll
        for (int r = 0; r < 4; ++r) {
            int row = q0 + w * 16 + lhi * 4 + r;
            float o = accO[d][r] / l_r[r];
            attn[(size_t)(b * T_ + row) * 1024 + h * 64 + d * 16 + l15] = f2bf(o);
        }
}

// ---------------------------------------------------------------------------
// Small elementwise kernels
// ---------------------------------------------------------------------------
__global__ __launch_bounds__(256)
void gather_k(const int* __restrict__ ids, const float* __restrict__ emb,
              float* __restrict__ x)
{
    int m = blockIdx.x, tid = threadIdx.x;
    int id = ids[m];
    *(f32x4*)(x + (size_t)m * D_ + tid * 4) =
        *(const f32x4*)(emb + (size_t)id * D_ + tid * 4);
}

__global__ __launch_bounds__(256)
void rmsnorm_k(const float* __restrict__ x, const float* __restrict__ g,
               u16* __restrict__ out)
{
    const int row = blockIdx.x, tid = threadIdx.x;
    const float* xr = x + (size_t)row * D_;
    f32x4 v = *(const f32x4*)(xr + tid * 4);
    float ss = v.x * v.x + v.y * v.y + v.z * v.z + v.w * v.w;
#pragma unroll
    for (int off = 32; off >= 1; off >>= 1) ss += __shfl_xor(ss, off);
    __shared__ float red[4];
    if ((tid & 63) == 0) red[tid >> 6] = ss;
    __syncthreads();
    float tot = red[0] + red[1] + red[2] + red[3];
    float rr = rsqrtf(tot * (1.0f / D_) + 1e-6f);
    f32x4 wv = *(const f32x4*)(g + tid * 4);
    u16x4 o;
    o.x = f2bf(v.x * rr * wv.x); o.y = f2bf(v.y * rr * wv.y);
    o.z = f2bf(v.z * rr * wv.z); o.w = f2bf(v.w * rr * wv.w);
    *(u16x4*)(out + (size_t)row * D_ + tid * 4) = o;
}

// cos/sin tables: tab[t*32 + j] = cos/sin(t * theta^(-j/32))
__global__ __launch_bounds__(256)
void rope_tab_k(float* __restrict__ tc, float* __restrict__ ts)
{
    int idx = blockIdx.x * 256 + threadIdx.x;
    int t = idx >> 5, j = idx & 31;
    float inv = powf(10000.0f, -(float)j * (1.0f / 32.0f));
    float ang = (float)t * inv;
    tc[idx] = cosf(ang);
    ts[idx] = sinf(ang);
}

// f32-silu (fallback path)
__global__ __launch_bounds__(256)
void silu_f32_k(const float* __restrict__ h13, u16* __restrict__ hh)
{
    int m = blockIdx.y;
    int f = blockIdx.x * 256 + threadIdx.x;
    float a = h13[(size_t)m * (2 * F_) + f];
    float c = h13[(size_t)m * (2 * F_) + F_ + f];
    float s = a / (1.0f + expf(-a));
    hh[(size_t)m * F_ + f] = f2bf(s * c);
}

__global__ __launch_bounds__(640)
void rope_slow_k(u16* __restrict__ qkv)
{
    int m = blockIdx.x;
    int c2 = threadIdx.x;
    int col = (c2 < 512) ? (c2 * 2) : (1024 + (c2 - 512) * 2);
    int d = col & 63;
    int t = m & (T_ - 1);
    float ang = (float)t * powf(10000.0f, -(float)d / 64.0f);
    float cs = cosf(ang), sn = sinf(ang);
    u16* p = qkv + (size_t)m * 1536 + col;
    float x0 = bf2f(p[0]), x1 = bf2f(p[1]);
    p[0] = f2bf(x0 * cs - x1 * sn);
    p[1] = f2bf(x0 * sn + x1 * cs);
}

// ---------------------------------------------------------------------------
extern "C" void kernel_launch(void* const* d_in, const int* in_sizes, int n_in,
                              void* d_out, int out_size, void* d_ws, size_t ws_size,
                              hipStream_t stream)
{
    const int*   ids = (const int*)d_in[0];
    const float* emb = (const float*)d_in[1];
    const float* qw  = (const float*)d_in[2];
    const float* kw  = (const float*)d_in[3];
    const float* vw  = (const float*)d_in[4];
    const float* ow  = (const float*)d_in[5];
    const float* w1  = (const float*)d_in[6];
    const float* w2  = (const float*)d_in[7];
    const float* w3  = (const float*)d_in[8];
    const float* n1  = (const float*)d_in[9];
    const float* n2  = (const float*)d_in[10];
    const float* nfw = (const float*)d_in[11];
    float* out = (float*)d_out;
    char*  ws  = (char*)d_ws;

    // ---- workspace layout ----
    float* x    = (float*)(ws);                    //  8 MB residual f32
    u16*   xn   = (u16*)(ws + 8388608ULL);         //  4 MB normed acts
    u16*   qkvb = (u16*)(ws + 12582912ULL);        //  6 MB fused qkv
    u16*   attnb= (u16*)(ws + 18874368ULL);        //  4 MB attn out
    u16*   hh   = (u16*)(ws + 46137344ULL);        // 11 MB silu(h1)*h3
    float* ropec= (float*)(ws + 57671680ULL);      // 128 KB
    float* ropes= (float*)(ws + 57802752ULL);      // 128 KB
    u16*   embb = (u16*)(ws + 57933824ULL);        // 62.5 MB
    u16*   wqkv = (u16*)(ws + 123469824ULL);       // 24 MB
    u16*   wob  = (u16*)(ws + 148635648ULL);       // 16 MB
    u16*   w13b = (u16*)(ws + 165412864ULL);       // 88 MB (w1/w3 row-interleaved)
    u16*   w2b  = (u16*)(ws + 257687552ULL);       // 44 MB
    u16*   vtb  = (u16*)(ws + 303824896ULL);       //  1 MB V^T
    const unsigned long long NEED = 304873472ULL;

    if (ws_size >= NEED) {
        cvt_k<<<dim3(32000, 1), 256, 0, stream>>>(emb, embb, 0, 0);
        cvt_k<<<dim3(1024, L_), 256, 0, stream>>>(qw, wqkv,            1048576ULL, 1572864ULL);
        cvt_k<<<dim3(256,  L_), 256, 0, stream>>>(kw, wqkv + 1048576,  262144ULL,  1572864ULL);
        cvt_k<<<dim3(256,  L_), 256, 0, stream>>>(vw, wqkv + 1310720,  262144ULL,  1572864ULL);
        cvt_k<<<dim3(1024, L_), 256, 0, stream>>>(ow, wob,             1048576ULL, 1048576ULL);
        cvt_il_k<<<dim3(2816, L_), 256, 0, stream>>>(w1, w13b, 2883584ULL, 5767168ULL, 0);
        cvt_il_k<<<dim3(2816, L_), 256, 0, stream>>>(w3, w13b, 2883584ULL, 5767168ULL, 1);
        cvt_k<<<dim3(2816, L_), 256, 0, stream>>>(w2, w2b,             2883584ULL, 2883584ULL);
        rope_tab_k<<<T_ * 32 / 256, 256, 0, stream>>>(ropec, ropes);

        gather_k<<<M_, 256, 0, stream>>>(ids, emb, x);

        for (int l = 0; l < L_; ++l) {
            rmsnorm_k<<<M_, 256, 0, stream>>>(x, n1 + l * D_, xn);
            // fused QKV + RoPE + V-transpose (v cols -> vtb, not qkvb)
            gemm2_k<64, 64, 4><<<32 * 24, 256, 0, stream>>>(
                xn, D_, wqkv + (size_t)l * 1572864, 1536, (float*)vtb, qkvb, ropec, ropes);
            attn2_k<<<dim3(T_ / 64, H_, B_), 256, 0, stream>>>(qkvb, vtb, attnb);
            gemm2_k<64, 64, 2><<<32 * 16, 256, 0, stream>>>(
                attnb, D_, wob + (size_t)l * 1048576, 1024, x, nullptr, nullptr, nullptr);
            rmsnorm_k<<<M_, 256, 0, stream>>>(x, n2 + l * D_, xn);
            // fused W1||W3 (interleaved) + SiLU -> hh
            gemm2_k<128, 128, 3><<<16 * 44, 256, 0, stream>>>(
                xn, D_, w13b + (size_t)l * 5767168, 5632, nullptr, hh, nullptr, nullptr);
            gemm2_k<64, 64, 2><<<32 * 16, 256, 0, stream>>>(
                hh, F_, w2b + (size_t)l * 2883584, 1024, x, nullptr, nullptr, nullptr);
        }

        rmsnorm_k<<<M_, 256, 0, stream>>>(x, nfw, xn);
        gemm2_k<128, 128, 1><<<16 * 250, 256, 0, stream>>>(
            xn, D_, embb, V_, out, nullptr, nullptr, nullptr);
        return;
    }

    // ---------------- fallback: round-1 proven path ----------------
    float* h13f = (float*)(ws + 23068672ULL);
    u16*   hhf  = (u16*)(ws + 69206016ULL);
    gather_k<<<M_, 256, 0, stream>>>(ids, emb, x);

    for (int l = 0; l < L_; ++l) {
        rmsnorm_k<<<M_, 256, 0, stream>>>(x, n1 + l * D_, xn);
        gemm_k<128, 64, 0, 3><<<dim3(24, 16), 256, 0, stream>>>(
            xn, D_,
            qw + (size_t)l * H_ * DH_ * D_,
            kw + (size_t)l * HK_ * DH_ * D_,
            vw + (size_t)l * HK_ * DH_ * D_,
            1024, 256, 1536, nullptr, qkvb);
        rope_slow_k<<<M_, 640, 0, stream>>>(qkvb);
        attn_k<<<dim3(T_ / 64, H_, B_), 256, 0, stream>>>(qkvb, attnb);
        gemm_k<128, 64, 2, 1><<<dim3(16, 16), 256, 0, stream>>>(
            attnb, D_, ow + (size_t)l * D_ * D_, nullptr, nullptr,
            0, 0, D_, x, nullptr);
        rmsnorm_k<<<M_, 256, 0, stream>>>(x, n2 + l * D_, xn);
        gemm_k<128, 128, 1, 2><<<dim3(44, 16), 256, 0, stream>>>(
            xn, D_, w1 + (size_t)l * F_ * D_, w3 + (size_t)l * F_ * D_, nullptr,
            F_, 0, 2 * F_, h13f, nullptr);
        silu_f32_k<<<dim3(11, M_), 256, 0, stream>>>(h13f, hhf);
        gemm_k<128, 64, 2, 1><<<dim3(16, 16), 256, 0, stream>>>(
            hhf, F_, w2 + (size_t)l * D_ * F_, nullptr, nullptr,
            0, 0, D_, x, nullptr);
    }

    rmsnorm_k<<<M_, 256, 0, stream>>>(x, nfw, xn);
    gemm_k<128, 128, 1, 1><<<dim3(250, 16), 256, 0, stream>>>(
        xn, D_, emb, nullptr, nullptr, 0, 0, V_, out, nullptr);
}

// Round 8
// 1806.522 us; speedup vs baseline: 1.1208x; 1.0101x over previous
//
#include <hip/hip_runtime.h>
#include <math.h>

#define L_ 8
#define D_ 1024
#define H_ 16
#define HK_ 4
#define DH_ 64
#define F_ 2816
#define V_ 32000
#define T_ 1024
#define B_ 2
#define M_ (B_*T_)          // 2048 tokens
#define SCALE_ 0.125f       // DH^-0.5

typedef unsigned short u16;
typedef unsigned int   u32;
typedef __attribute__((ext_vector_type(4))) float  f32x4;
typedef __attribute__((ext_vector_type(8))) short  bf16x8;   // 8 bf16 = 4 VGPRs (MFMA A/B frag)
typedef __attribute__((ext_vector_type(4))) unsigned short u16x4;
typedef __attribute__((ext_vector_type(4))) unsigned int   u32x4;

__device__ __forceinline__ float bf2f(u16 h) {
    union { u32 u; float f; } v; v.u = ((u32)h) << 16; return v.f;
}
__device__ __forceinline__ u16 f2bf(float f) {   // round-to-nearest-even
    union { float f; u32 u; } v; v.f = f;
    u32 r = v.u + 0x7fffu + ((v.u >> 16) & 1u);
    return (u16)(r >> 16);
}

__device__ __forceinline__ void gl_lds16(const void* g, void* l) {
    __builtin_amdgcn_global_load_lds(
        (const __attribute__((address_space(1))) unsigned int*)g,
        (__attribute__((address_space(3))) unsigned int*)l,
        16, 0, 0);
}

// ---------------------------------------------------------------------------
// 2-phase double-buffered GEMM (proven): C[M,N]=A[M,K] x W[N,K]^T, bf16.
// BK=32, 4 waves 2x2, bijective XCD swizzle, global_load_lds staging.
// EPI: 0 = bf16 store, 1 = f32 store, 2 = f32 +=,
//      3 = fused SiLU (w1/w3 row-interleaved; even col=h1, odd=h3 -> Ob[M][F_])
//      4 = fused RoPE (cols<1280 rotated; v cols 1280..1536 -> vt (via Of))
// ---------------------------------------------------------------------------
template<int BM, int BN, int EPI>
__global__ __launch_bounds__(256)
void gemm2_k(const u16* __restrict__ A, int K,
             const u16* __restrict__ W, int N,
             float* __restrict__ Of, u16* __restrict__ Ob,
             const float* __restrict__ tc, const float* __restrict__ ts)
{
    constexpr int FM = BM / 32;
    constexpr int FN = BN / 32;
    constexpr int GM = M_ / BM;
    constexpr int IPA = BM / 64;
    constexpr int IPB = BN / 64;
    __shared__ u16 sA[2 * BM * 32];
    __shared__ u16 sB[2 * BN * 32];

    const int tid  = threadIdx.x;
    const int lane = tid & 63, wv = tid >> 6;
    const int wm = wv >> 1, wn = wv & 1;
    const int l15 = lane & 15, lhi = lane >> 4;
    const int m0 = wm * (BM / 2), n0 = wn * (BN / 2);

    const int nwg = gridDim.x;
    const int q8 = nwg >> 3, r8 = nwg & 7;
    const int xcd = blockIdx.x & 7, off8 = blockIdx.x >> 3;
    const int wgid = (xcd < r8 ? xcd * (q8 + 1) : r8 * (q8 + 1) + (xcd - r8) * q8) + off8;
    const int tM = wgid % GM, tN = wgid / GM;

    const int srow = lane >> 2;
    const int scol = (lane & 3) * 8;

    const u16* Abase = A + (size_t)(tM * BM) * K;
    const u16* Wbase = W + (size_t)(tN * BN) * K;

    f32x4 acc[FM][FN];
#pragma unroll
    for (int i = 0; i < FM; ++i)
#pragma unroll
        for (int j = 0; j < FN; ++j) acc[i][j] = f32x4{0.f, 0.f, 0.f, 0.f};

    auto stage = [&](int kt, int buf) {
        u16* sa = sA + buf * (BM * 32);
        u16* sb = sB + buf * (BN * 32);
#pragma unroll
        for (int i = 0; i < IPA; ++i) {
            int c = wv * IPA + i;
            gl_lds16(Abase + (size_t)(c * 16 + srow) * K + kt + scol, sa + c * 512);
        }
#pragma unroll
        for (int i = 0; i < IPB; ++i) {
            int c = wv * IPB + i;
            gl_lds16(Wbase + (size_t)(c * 16 + srow) * K + kt + scol, sb + c * 512);
        }
    };

    const int nt = K >> 5;
    stage(0, 0);
    asm volatile("s_waitcnt vmcnt(0)" ::: "memory");
    __syncthreads();

    int cur = 0;
    for (int t = 0; t < nt; ++t) {
        if (t + 1 < nt) stage((t + 1) << 5, cur ^ 1);

        const u16* sa = sA + cur * (BM * 32);
        const u16* sb = sB + cur * (BN * 32);
        bf16x8 av[FM], bv[FN];
#pragma unroll
        for (int i = 0; i < FM; ++i)
            av[i] = *(const bf16x8*)&sa[(m0 + i * 16 + l15) * 32 + lhi * 8];
#pragma unroll
        for (int j = 0; j < FN; ++j)
            bv[j] = *(const bf16x8*)&sb[(n0 + j * 16 + l15) * 32 + lhi * 8];
#pragma unroll
        for (int i = 0; i < FM; ++i)
#pragma unroll
            for (int j = 0; j < FN; ++j)
                acc[i][j] = __builtin_amdgcn_mfma_f32_16x16x32_bf16(
                    av[i], bv[j], acc[i][j], 0, 0, 0);

        if (t + 1 < nt) {
            asm volatile("s_waitcnt vmcnt(0)" ::: "memory");
            __syncthreads();
            cur ^= 1;
        }
    }

    // epilogue: D col = lane&15, row = (lane>>4)*4 + reg
#pragma unroll
    for (int i = 0; i < FM; ++i)
#pragma unroll
        for (int j = 0; j < FN; ++j) {
            size_t gm = (size_t)tM * BM + m0 + i * 16 + lhi * 4;
            size_t gn = (size_t)tN * BN + n0 + j * 16 + l15;
#pragma unroll
            for (int r = 0; r < 4; ++r) {
                float v = acc[i][j][r];
                size_t idx = (gm + r) * (size_t)N + gn;
                if (EPI == 0) {
                    Ob[idx] = f2bf(v);
                } else if (EPI == 1) {
                    Of[idx] = v;
                } else if (EPI == 2) {
                    Of[idx] += v;
                } else if (EPI == 3) {
                    float b = __shfl_xor(v, 1);
                    if ((lane & 1) == 0) {
                        float s = v / (1.0f + expf(-v));
                        Ob[(gm + r) * (size_t)F_ + (gn >> 1)] = f2bf(s * b);
                    }
                } else {   // EPI == 4: RoPE q/k; v cols -> transposed vt
                    float b = __shfl_xor(v, 1);
                    int gni = (int)gn;
                    int gmr = (int)(gm + r);
                    if (gni < 1280) {
                        int dd = gni & 63;
                        int jj = dd >> 1;
                        int tt = gmr & (T_ - 1);
                        float c = tc[tt * 32 + jj], s = ts[tt * 32 + jj];
                        float ro = ((dd & 1) == 0) ? (v * c - b * s) : (b * s + v * c);
                        Ob[idx] = f2bf(ro);
                    } else {
                        int vc = gni - 1280;              // 0..255
                        int hk = vc >> 6, dd = vc & 63;
                        int bb = gmr >> 10, tt = gmr & (T_ - 1);
                        ((u16*)Of)[((size_t)((bb * HK_ + hk) * DH_ + dd)) * T_ + tt] = f2bf(v);
                    }
                }
            }
        }
}

// f32 -> bf16 layer-strided conversion
__global__ __launch_bounds__(256)
void cvt_k(const float* __restrict__ src, u16* __restrict__ dst,
           unsigned long long sStride, unsigned long long dStride)
{
    int l = blockIdx.y;
    size_t i = ((size_t)blockIdx.x * 256 + threadIdx.x) * 4;
    f32x4 v = *(const f32x4*)(src + l * sStride + i);
    u16x4 o;
    o.x = f2bf(v.x); o.y = f2bf(v.y); o.z = f2bf(v.z); o.w = f2bf(v.w);
    *(u16x4*)(dst + l * dStride + i) = o;
}

// f32 -> bf16 with row interleave: src row f -> dst row 2f+off (rows of D_)
__global__ __launch_bounds__(256)
void cvt_il_k(const float* __restrict__ src, u16* __restrict__ dst,
              unsigned long long sStride, unsigned long long dStride, int off)
{
    int f = blockIdx.x, l = blockIdx.y;
    int i = threadIdx.x * 4;
    f32x4 v = *(const f32x4*)(src + l * sStride + (size_t)f * D_ + i);
    u16x4 o;
    o.x = f2bf(v.x); o.y = f2bf(v.y); o.z = f2bf(v.z); o.w = f2bf(v.w);
    *(u16x4*)(dst + l * dStride + (size_t)(2 * f + off) * D_ + i) = o;
}

// ---------------------------------------------------------------------------
// FALLBACK GEMM (round-1, proven): cast-in-staging, multi-W split.
// ---------------------------------------------------------------------------
template<int BM, int BN, int EPI, int NW>
__global__ __launch_bounds__(256)
void gemm_k(const u16* __restrict__ A, int K,
            const float* __restrict__ W0, const float* __restrict__ W1p,
            const float* __restrict__ W2p, int N0, int N1, int N,
            float* __restrict__ Of, u16* __restrict__ Ob)
{
    constexpr int FM = BM / 32;
    constexpr int FN = BN / 32;
    constexpr int LS = 40;
    __shared__ u16 sA[BM * LS];
    __shared__ u16 sB[BN * LS];

    const int tid  = threadIdx.x;
    const int lane = tid & 63, wv = tid >> 6;
    const int wm = wv >> 1, wn = wv & 1;
    const int l15 = lane & 15, lhi = lane >> 4;
    const int m0 = wm * (BM / 2), n0 = wn * (BN / 2);
    const int tM = blockIdx.y, tN = blockIdx.x;

    f32x4 acc[FM][FN];
#pragma unroll
    for (int i = 0; i < FM; ++i)
#pragma unroll
        for (int j = 0; j < FN; ++j) acc[i][j] = f32x4{0.f, 0.f, 0.f, 0.f};

    for (int kt = 0; kt < K; kt += 32) {
#pragma unroll
        for (int i = 0; i < BM / 64; ++i) {
            int cid = tid + i * 256;
            int row = cid >> 2, kc = cid & 3;
            const u16* src = A + (size_t)(tM * BM + row) * K + kt + kc * 8;
            *(u32x4*)&sA[row * LS + kc * 8] = *(const u32x4*)src;
        }
#pragma unroll
        for (int i = 0; i < BN / 32; ++i) {
            int cid = tid + i * 256;
            int row = cid >> 3, kc = cid & 7;
            int n = tN * BN + row;
            const float* wr;
            if (NW == 1)      wr = W0 + (size_t)n * K;
            else if (NW == 2) wr = (n < N0) ? (W0 + (size_t)n * K)
                                            : (W1p + (size_t)(n - N0) * K);
            else              wr = (n < N0) ? (W0 + (size_t)n * K)
                               : (n < N0 + N1) ? (W1p + (size_t)(n - N0) * K)
                                               : (W2p + (size_t)(n - N0 - N1) * K);
            f32x4 v = *(const f32x4*)(wr + kt + kc * 4);
            u16x4 o;
            o.x = f2bf(v.x); o.y = f2bf(v.y); o.z = f2bf(v.z); o.w = f2bf(v.w);
            *(u16x4*)&sB[row * LS + kc * 4] = o;
        }
        __syncthreads();

        bf16x8 av[FM], bv[FN];
#pragma unroll
        for (int i = 0; i < FM; ++i)
            av[i] = *(const bf16x8*)&sA[(m0 + i * 16 + l15) * LS + lhi * 8];
#pragma unroll
        for (int j = 0; j < FN; ++j)
            bv[j] = *(const bf16x8*)&sB[(n0 + j * 16 + l15) * LS + lhi * 8];
#pragma unroll
        for (int i = 0; i < FM; ++i)
#pragma unroll
            for (int j = 0; j < FN; ++j)
                acc[i][j] = __builtin_amdgcn_mfma_f32_16x16x32_bf16(
                    av[i], bv[j], acc[i][j], 0, 0, 0);
        __syncthreads();
    }

#pragma unroll
    for (int i = 0; i < FM; ++i)
#pragma unroll
        for (int j = 0; j < FN; ++j) {
            size_t gm = (size_t)tM * BM + m0 + i * 16 + lhi * 4;
            size_t gn = (size_t)tN * BN + n0 + j * 16 + l15;
#pragma unroll
            for (int r = 0; r < 4; ++r) {
                float v = acc[i][j][r];
                size_t idx = (gm + r) * (size_t)N + gn;
                if (EPI == 0)      Ob[idx] = f2bf(v);
                else if (EPI == 1) Of[idx] = v;
                else               Of[idx] += v;
            }
        }
}

// ---------------------------------------------------------------------------
// Flash attention v3: GQA-shared K/V staging. Grid (32, HK, B), 512 threads
// (8 waves). Block = 4 q-heads x 32 q-rows of one kv-group; wave w handles
// 16 rows (w>>2 row-group) of head hk*4+(w&3). K/V^T staged ONCE per tile
// for all 4 heads. KVBLK=128, slot-swizzled, same inner math as proven v2.
// ---------------------------------------------------------------------------
__global__ __launch_bounds__(512)
void attn3_k(const u16* __restrict__ qkv, const u16* __restrict__ vt,
             u16* __restrict__ attn)
{
    const int qt = 31 - blockIdx.x;              // long blocks first
    const int hk = blockIdx.y, b = blockIdx.z;
    const int tid = threadIdx.x;
    const int lane = tid & 63, w = tid >> 6;     // 8 waves
    const int l15 = lane & 15, lhi = lane >> 4;
    const int h = hk * 4 + (w & 3);
    const int rg = w >> 2;                       // row-group 0/1

    __shared__ u16 sK[128 * 64];                 // [kv][d], slot-swizzled
    __shared__ u16 sVT[64 * 128];                // [d][kv], slot-swizzled
    __shared__ u16 sP[8][16 * 136];              // per-wave P

    const int q0 = qt * 32;
    const int qr0 = q0 + rg * 16;
    const u16* qptr = qkv + (size_t)(b * T_ + qr0 + l15) * 1536 + h * 64 + lhi * 8;
    bf16x8 aq0 = *(const bf16x8*)qptr;
    bf16x8 aq1 = *(const bf16x8*)(qptr + 32);

    f32x4 accO[4];
#pragma unroll
    for (int d = 0; d < 4; ++d) accO[d] = f32x4{0.f, 0.f, 0.f, 0.f};
    float m_r[4] = {-1e30f, -1e30f, -1e30f, -1e30f};
    float l_r[4] = {0.f, 0.f, 0.f, 0.f};
    const int myq = qr0 + lhi * 4;
    const int qmaxw = qr0 + 15;
    u16* sPw = sP[w];

    const int ntiles = (qt >> 2) + 1;
    const u16* vtb = vt + (size_t)((b * HK_ + hk) * DH_) * T_;
    const int L = lane;

    for (int kt = 0; kt < ntiles; ++kt) {
        const int t0 = kt * 128;
        // ---- stage K tile (128 x 64): 16 chunks over 8 waves ----
#pragma unroll
        for (int i = 0; i < 2; ++i) {
            int c = w * 2 + i;
            int row = c * 8 + (L >> 3);
            int p = L & 7;
            const u16* src = qkv + (size_t)(b * T_ + t0 + row) * 1536 + 1024 + hk * 64
                             + ((p ^ (row & 7)) * 8);
            gl_lds16(src, sK + c * 512);
        }
        // ---- stage V^T tile (64 x 128): 16 chunks over 8 waves ----
#pragma unroll
        for (int i = 0; i < 2; ++i) {
            int c = w * 2 + i;
            int row = c * 4 + (L >> 4);
            int p = L & 15;
            const u16* src = vtb + (size_t)row * T_ + t0 + ((p ^ (row & 15)) * 8);
            gl_lds16(src, sVT + c * 512);
        }
        asm volatile("s_waitcnt vmcnt(0)" ::: "memory");
        __syncthreads();

        const bool lastt = (kt == ntiles - 1);

        f32x4 accS[8];
#pragma unroll
        for (int nf = 0; nf < 8; ++nf)
            accS[nf] = f32x4{-1e30f, -1e30f, -1e30f, -1e30f};
#pragma unroll
        for (int pk = 0; pk < 4; ++pk) {
            if (t0 + pk * 32 > qmaxw) continue;
            f32x4 s0 = f32x4{0.f, 0.f, 0.f, 0.f};
            f32x4 s1 = f32x4{0.f, 0.f, 0.f, 0.f};
#pragma unroll
            for (int kk = 0; kk < 2; ++kk) {
                bf16x8 aqs = kk ? aq1 : aq0;
                int r0 = (pk * 2) * 16 + l15;
                int r1 = (pk * 2 + 1) * 16 + l15;
                int ls = kk * 4 + lhi;
                bf16x8 b0 = *(const bf16x8*)&sK[r0 * 64 + ((ls ^ (r0 & 7)) * 8)];
                bf16x8 b1 = *(const bf16x8*)&sK[r1 * 64 + ((ls ^ (r1 & 7)) * 8)];
                s0 = __builtin_amdgcn_mfma_f32_16x16x32_bf16(aqs, b0, s0, 0, 0, 0);
                s1 = __builtin_amdgcn_mfma_f32_16x16x32_bf16(aqs, b1, s1, 0, 0, 0);
            }
#pragma unroll
            for (int r = 0; r < 4; ++r) {
                float v0 = s0[r] * SCALE_;
                float v1 = s1[r] * SCALE_;
                if (lastt) {
                    int kp0 = t0 + (pk * 2) * 16 + l15;
                    int kp1 = kp0 + 16;
                    if (kp0 > myq + r) v0 = -1e30f;
                    if (kp1 > myq + r) v1 = -1e30f;
                }
                accS[pk * 2][r] = v0;
                accS[pk * 2 + 1][r] = v1;
            }
        }

        float sc[4];
#pragma unroll
        for (int r = 0; r < 4; ++r) {
            float mx = accS[0][r];
#pragma unroll
            for (int nf = 1; nf < 8; ++nf) mx = fmaxf(mx, accS[nf][r]);
#pragma unroll
            for (int off = 1; off < 16; off <<= 1) mx = fmaxf(mx, __shfl_xor(mx, off));
            float mn = fmaxf(m_r[r], mx);
            sc[r] = expf(m_r[r] - mn);
            m_r[r] = mn;
        }
        float rs[4] = {0.f, 0.f, 0.f, 0.f};
#pragma unroll
        for (int pk = 0; pk < 4; ++pk) {
            if (t0 + pk * 32 > qmaxw) continue;
#pragma unroll
            for (int g = 0; g < 2; ++g) {
                int nf = pk * 2 + g;
#pragma unroll
                for (int r = 0; r < 4; ++r) {
                    float p = expf(accS[nf][r] - m_r[r]);
                    accS[nf][r] = p;
                    rs[r] += p;
                }
            }
        }
#pragma unroll
        for (int r = 0; r < 4; ++r) {
#pragma unroll
            for (int off = 1; off < 16; off <<= 1) rs[r] += __shfl_xor(rs[r], off);
            l_r[r] = l_r[r] * sc[r] + rs[r];
        }
#pragma unroll
        for (int d = 0; d < 4; ++d)
#pragma unroll
            for (int r = 0; r < 4; ++r) accO[d][r] *= sc[r];

#pragma unroll
        for (int pk = 0; pk < 4; ++pk) {
            if (t0 + pk * 32 > qmaxw) continue;
#pragma unroll
            for (int g = 0; g < 2; ++g) {
                int nf = pk * 2 + g;
#pragma unroll
                for (int r = 0; r < 4; ++r)
                    sPw[(lhi * 4 + r) * 136 + nf * 16 + l15] = f2bf(accS[nf][r]);
            }
        }

#pragma unroll
        for (int kk = 0; kk < 4; ++kk) {
            if (t0 + kk * 32 > qmaxw) continue;
            bf16x8 pas = *(const bf16x8*)&sPw[l15 * 136 + kk * 32 + lhi * 8];
#pragma unroll
            for (int nf = 0; nf < 4; ++nf) {
                int row = nf * 16 + l15;
                int ls = kk * 4 + lhi;
                bf16x8 bvv = *(const bf16x8*)&sVT[row * 128 + ((ls ^ (row & 15)) * 8)];
                accO[nf] = __builtin_amdgcn_mfma_f32_16x16x32_bf16(pas, bvv, accO[nf], 0, 0, 0);
            }
        }
        __syncthreads();
    }

#pragma unroll
    for (int d = 0; d < 4; ++d)
#pragma unroll
        for (int r = 0; r < 4; ++r) {
            int row = qr0 + lhi * 4 + r;
            float o = accO[d][r] / l_r[r];
            attn[(size_t)(b * T_ + row) * 1024 + h * 64 + d * 16 + l15] = f2bf(o);
        }
}

// ---------------------------------------------------------------------------
// FALLBACK attention (round-1 proven)
// ---------------------------------------------------------------------------
__global__ __launch_bounds__(256)
void attn_k(const u16* __restrict__ qkv, u16* __restrict__ attn)
{
    const int qt = blockIdx.x, h = blockIdx.y, b = blockIdx.z;
    const int hk = h >> 2;
    const int tid = threadIdx.x;
    const int lane = tid & 63, w = tid >> 6;
    const int l15 = lane & 15, lhi = lane >> 4;
    __shared__ u16 sK[64 * 72];
    __shared__ u16 sVT[64 * 74];
    __shared__ u16 sP[4 * 16 * 72];

    const int q0 = qt * 64;
    const u16* qptr = qkv + (size_t)(b * T_ + q0 + w * 16 + l15) * 1536 + h * 64 + lhi * 8;
    bf16x8 aq0 = *(const bf16x8*)qptr;
    bf16x8 aq1 = *(const bf16x8*)(qptr + 32);

    f32x4 accO[4];
#pragma unroll
    for (int d = 0; d < 4; ++d) accO[d] = f32x4{0.f, 0.f, 0.f, 0.f};
    float m_r[4] = {-1e30f, -1e30f, -1e30f, -1e30f};
    float l_r[4] = {0.f, 0.f, 0.f, 0.f};
    const int myq = q0 + w * 16 + lhi * 4;
    u16* sPw = sP + w * 16 * 72;

    for (int kt = 0; kt <= qt; ++kt) {
#pragma unroll
        for (int i = 0; i < 2; ++i) {
            int cid = tid + i * 256;
            int r = cid >> 3, kc = cid & 7;
            const u16* src = qkv + (size_t)(b * T_ + kt * 64 + r) * 1536 + 1024 + hk * 64 + kc * 8;
            *(u32x4*)&sK[r * 72 + kc * 8] = *(const u32x4*)src;
        }
#pragma unroll
        for (int i = 0; i < 2; ++i) {
            int cid = tid + i * 256;
            int tt = cid >> 3, dc = cid & 7;
            const u16* src = qkv + (size_t)(b * T_ + kt * 64 + tt) * 1536 + 1280 + hk * 64 + dc * 8;
            bf16x8 vv = *(const bf16x8*)src;
#pragma unroll
            for (int j = 0; j < 8; ++j) sVT[(dc * 8 + j) * 74 + tt] = (u16)vv[j];
        }
        __syncthreads();

        f32x4 accS[4];
#pragma unroll
        for (int nf = 0; nf < 4; ++nf) accS[nf] = f32x4{0.f, 0.f, 0.f, 0.f};
#pragma unroll
        for (int s = 0; s < 2; ++s) {
            bf16x8 aqs = s ? aq1 : aq0;
#pragma unroll
            for (int nf = 0; nf < 4; ++nf) {
                bf16x8 bk = *(const bf16x8*)&sK[(nf * 16 + l15) * 72 + s * 32 + lhi * 8];
                accS[nf] = __builtin_amdgcn_mfma_f32_16x16x32_bf16(aqs, bk, accS[nf], 0, 0, 0);
            }
        }
#pragma unroll
        for (int nf = 0; nf < 4; ++nf)
#pragma unroll
            for (int r = 0; r < 4; ++r) {
                float v = accS[nf][r] * SCALE_;
                if (kt == qt) {
                    int kp = kt * 64 + nf * 16 + l15;
                    if (kp > myq + r) v = -1e30f;
                }
                accS[nf][r] = v;
            }
        float sc[4];
#pragma unroll
        for (int r = 0; r < 4; ++r) {
            float mx = fmaxf(fmaxf(accS[0][r], accS[1][r]), fmaxf(accS[2][r], accS[3][r]));
#pragma unroll
            for (int off = 1; off < 16; off <<= 1) mx = fmaxf(mx, __shfl_xor(mx, off));
            float mn = fmaxf(m_r[r], mx);
            sc[r] = expf(m_r[r] - mn);
            m_r[r] = mn;
        }
        float rs[4] = {0.f, 0.f, 0.f, 0.f};
#pragma unroll
        for (int nf = 0; nf < 4; ++nf)
#pragma unroll
            for (int r = 0; r < 4; ++r) {
                float p = expf(accS[nf][r] - m_r[r]);
                accS[nf][r] = p;
                rs[r] += p;
            }
#pragma unroll
        for (int r = 0; r < 4; ++r) {
#pragma unroll
            for (int off = 1; off < 16; off <<= 1) rs[r] += __shfl_xor(rs[r], off);
            l_r[r] = l_r[r] * sc[r] + rs[r];
        }
#pragma unroll
        for (int d = 0; d < 4; ++d)
#pragma unroll
            for (int r = 0; r < 4; ++r) accO[d][r] *= sc[r];

#pragma unroll
        for (int nf = 0; nf < 4; ++nf)
#pragma unroll
            for (int r = 0; r < 4; ++r)
                sPw[(lhi * 4 + r) * 72 + nf * 16 + l15] = f2bf(accS[nf][r]);
        bf16x8 pa0 = *(const bf16x8*)&sPw[l15 * 72 + lhi * 8];
        bf16x8 pa1 = *(const bf16x8*)&sPw[l15 * 72 + 32 + lhi * 8];
#pragma unroll
        for (int s = 0; s < 2; ++s) {
            bf16x8 pas = s ? pa1 : pa0;
#pragma unroll
            for (int d = 0; d < 4; ++d) {
                bf16x8 bvv = *(const bf16x8*)&sVT[(d * 16 + l15) * 74 + s * 32 + lhi * 8];
                accO[d] = __builtin_amdgcn_mfma_f32_16x16x32_bf16(pas, bvv, accO[d], 0, 0, 0);
            }
        }
        __syncthreads();
    }

#pragma unroll
    for (int d = 0; d < 4; ++d)
#pragma unroll
        for (int r = 0; r < 4; ++r) {
            int row = q0 + w * 16 + lhi * 4 + r;
            float o = accO[d][r] / l_r[r];
            attn[(size_t)(b * T_ + row) * 1024 + h * 64 + d * 16 + l15] = f2bf(o);
        }
}

// ---------------------------------------------------------------------------
// Small elementwise kernels
// ---------------------------------------------------------------------------
__global__ __launch_bounds__(256)
void gather_k(const int* __restrict__ ids, const float* __restrict__ emb,
              float* __restrict__ x)
{
    int m = blockIdx.x, tid = threadIdx.x;
    int id = ids[m];
    *(f32x4*)(x + (size_t)m * D_ + tid * 4) =
        *(const f32x4*)(emb + (size_t)id * D_ + tid * 4);
}

__global__ __launch_bounds__(256)
void rmsnorm_k(const float* __restrict__ x, const float* __restrict__ g,
               u16* __restrict__ out)
{
    const int row = blockIdx.x, tid = threadIdx.x;
    const float* xr = x + (size_t)row * D_;
    f32x4 v = *(const f32x4*)(xr + tid * 4);
    float ss = v.x * v.x + v.y * v.y + v.z * v.z + v.w * v.w;
#pragma unroll
    for (int off = 32; off >= 1; off >>= 1) ss += __shfl_xor(ss, off);
    __shared__ float red[4];
    if ((tid & 63) == 0) red[tid >> 6] = ss;
    __syncthreads();
    float tot = red[0] + red[1] + red[2] + red[3];
    float rr = rsqrtf(tot * (1.0f / D_) + 1e-6f);
    f32x4 wv = *(const f32x4*)(g + tid * 4);
    u16x4 o;
    o.x = f2bf(v.x * rr * wv.x); o.y = f2bf(v.y * rr * wv.y);
    o.z = f2bf(v.z * rr * wv.z); o.w = f2bf(v.w * rr * wv.w);
    *(u16x4*)(out + (size_t)row * D_ + tid * 4) = o;
}

// cos/sin tables: tab[t*32 + j] = cos/sin(t * theta^(-j/32))
__global__ __launch_bounds__(256)
void rope_tab_k(float* __restrict__ tc, float* __restrict__ ts)
{
    int idx = blockIdx.x * 256 + threadIdx.x;
    int t = idx >> 5, j = idx & 31;
    float inv = powf(10000.0f, -(float)j * (1.0f / 32.0f));
    float ang = (float)t * inv;
    tc[idx] = cosf(ang);
    ts[idx] = sinf(ang);
}

// f32-silu (fallback path)
__global__ __launch_bounds__(256)
void silu_f32_k(const float* __restrict__ h13, u16* __restrict__ hh)
{
    int m = blockIdx.y;
    int f = blockIdx.x * 256 + threadIdx.x;
    float a = h13[(size_t)m * (2 * F_) + f];
    float c = h13[(size_t)m * (2 * F_) + F_ + f];
    float s = a / (1.0f + expf(-a));
    hh[(size_t)m * F_ + f] = f2bf(s * c);
}

__global__ __launch_bounds__(640)
void rope_slow_k(u16* __restrict__ qkv)
{
    int m = blockIdx.x;
    int c2 = threadIdx.x;
    int col = (c2 < 512) ? (c2 * 2) : (1024 + (c2 - 512) * 2);
    int d = col & 63;
    int t = m & (T_ - 1);
    float ang = (float)t * powf(10000.0f, -(float)d / 64.0f);
    float cs = cosf(ang), sn = sinf(ang);
    u16* p = qkv + (size_t)m * 1536 + col;
    float x0 = bf2f(p[0]), x1 = bf2f(p[1]);
    p[0] = f2bf(x0 * cs - x1 * sn);
    p[1] = f2bf(x0 * sn + x1 * cs);
}

// ---------------------------------------------------------------------------
extern "C" void kernel_launch(void* const* d_in, const int* in_sizes, int n_in,
                              void* d_out, int out_size, void* d_ws, size_t ws_size,
                              hipStream_t stream)
{
    const int*   ids = (const int*)d_in[0];
    const float* emb = (const float*)d_in[1];
    const float* qw  = (const float*)d_in[2];
    const float* kw  = (const float*)d_in[3];
    const float* vw  = (const float*)d_in[4];
    const float* ow  = (const float*)d_in[5];
    const float* w1  = (const float*)d_in[6];
    const float* w2  = (const float*)d_in[7];
    const float* w3  = (const float*)d_in[8];
    const float* n1  = (const float*)d_in[9];
    const float* n2  = (const float*)d_in[10];
    const float* nfw = (const float*)d_in[11];
    float* out = (float*)d_out;
    char*  ws  = (char*)d_ws;

    // ---- workspace layout ----
    float* x    = (float*)(ws);                    //  8 MB residual f32
    u16*   xn   = (u16*)(ws + 8388608ULL);         //  4 MB normed acts
    u16*   qkvb = (u16*)(ws + 12582912ULL);        //  6 MB fused qkv
    u16*   attnb= (u16*)(ws + 18874368ULL);        //  4 MB attn out
    u16*   hh   = (u16*)(ws + 46137344ULL);        // 11 MB silu(h1)*h3
    float* ropec= (float*)(ws + 57671680ULL);      // 128 KB
    float* ropes= (float*)(ws + 57802752ULL);      // 128 KB
    u16*   embb = (u16*)(ws + 57933824ULL);        // 62.5 MB
    u16*   wqkv = (u16*)(ws + 123469824ULL);       // 24 MB
    u16*   wob  = (u16*)(ws + 148635648ULL);       // 16 MB
    u16*   w13b = (u16*)(ws + 165412864ULL);       // 88 MB (w1/w3 row-interleaved)
    u16*   w2b  = (u16*)(ws + 257687552ULL);       // 44 MB
    u16*   vtb  = (u16*)(ws + 303824896ULL);       //  1 MB V^T
    const unsigned long long NEED = 304873472ULL;

    if (ws_size >= NEED) {
        cvt_k<<<dim3(32000, 1), 256, 0, stream>>>(emb, embb, 0, 0);
        cvt_k<<<dim3(1024, L_), 256, 0, stream>>>(qw, wqkv,            1048576ULL, 1572864ULL);
        cvt_k<<<dim3(256,  L_), 256, 0, stream>>>(kw, wqkv + 1048576,  262144ULL,  1572864ULL);
        cvt_k<<<dim3(256,  L_), 256, 0, stream>>>(vw, wqkv + 1310720,  262144ULL,  1572864ULL);
        cvt_k<<<dim3(1024, L_), 256, 0, stream>>>(ow, wob,             1048576ULL, 1048576ULL);
        cvt_il_k<<<dim3(2816, L_), 256, 0, stream>>>(w1, w13b, 2883584ULL, 5767168ULL, 0);
        cvt_il_k<<<dim3(2816, L_), 256, 0, stream>>>(w3, w13b, 2883584ULL, 5767168ULL, 1);
        cvt_k<<<dim3(2816, L_), 256, 0, stream>>>(w2, w2b,             2883584ULL, 2883584ULL);
        rope_tab_k<<<T_ * 32 / 256, 256, 0, stream>>>(ropec, ropes);

        gather_k<<<M_, 256, 0, stream>>>(ids, emb, x);

        for (int l = 0; l < L_; ++l) {
            rmsnorm_k<<<M_, 256, 0, stream>>>(x, n1 + l * D_, xn);
            // fused QKV + RoPE + V-transpose (v cols -> vtb, not qkvb)
            gemm2_k<64, 64, 4><<<32 * 24, 256, 0, stream>>>(
                xn, D_, wqkv + (size_t)l * 1572864, 1536, (float*)vtb, qkvb, ropec, ropes);
            attn3_k<<<dim3(32, HK_, B_), 512, 0, stream>>>(qkvb, vtb, attnb);
            gemm2_k<64, 64, 2><<<32 * 16, 256, 0, stream>>>(
                attnb, D_, wob + (size_t)l * 1048576, 1024, x, nullptr, nullptr, nullptr);
            rmsnorm_k<<<M_, 256, 0, stream>>>(x, n2 + l * D_, xn);
            // fused W1||W3 (interleaved) + SiLU -> hh
            gemm2_k<128, 128, 3><<<16 * 44, 256, 0, stream>>>(
                xn, D_, w13b + (size_t)l * 5767168, 5632, nullptr, hh, nullptr, nullptr);
            gemm2_k<64, 64, 2><<<32 * 16, 256, 0, stream>>>(
                hh, F_, w2b + (size_t)l * 2883584, 1024, x, nullptr, nullptr, nullptr);
        }

        rmsnorm_k<<<M_, 256, 0, stream>>>(x, nfw, xn);
        gemm2_k<128, 128, 1><<<16 * 250, 256, 0, stream>>>(
            xn, D_, embb, V_, out, nullptr, nullptr, nullptr);
        return;
    }

    // ---------------- fallback: round-1 proven path ----------------
    float* h13f = (float*)(ws + 23068672ULL);
    u16*   hhf  = (u16*)(ws + 69206016ULL);
    gather_k<<<M_, 256, 0, stream>>>(ids, emb, x);

    for (int l = 0; l < L_; ++l) {
        rmsnorm_k<<<M_, 256, 0, stream>>>(x, n1 + l * D_, xn);
        gemm_k<128, 64, 0, 3><<<dim3(24, 16), 256, 0, stream>>>(
            xn, D_,
            qw + (size_t)l * H_ * DH_ * D_,
            kw + (size_t)l * HK_ * DH_ * D_,
            vw + (size_t)l * HK_ * DH_ * D_,
            1024, 256, 1536, nullptr, qkvb);
        rope_slow_k<<<M_, 640, 0, stream>>>(qkvb);
        attn_k<<<dim3(T_ / 64, H_, B_), 256, 0, stream>>>(qkvb, attnb);
        gemm_k<128, 64, 2, 1><<<dim3(16, 16), 256, 0, stream>>>(
            attnb, D_, ow + (size_t)l * D_ * D_, nullptr, nullptr,
            0, 0, D_, x, nullptr);
        rmsnorm_k<<<M_, 256, 0, stream>>>(x, n2 + l * D_, xn);
        gemm_k<128, 128, 1, 2><<<dim3(44, 16), 256, 0, stream>>>(
            xn, D_, w1 + (size_t)l * F_ * D_, w3 + (size_t)l * F_ * D_, nullptr,
            F_, 0, 2 * F_, h13f, nullptr);
        silu_f32_k<<<dim3(11, M_), 256, 0, stream>>>(h13f, hhf);
        gemm_k<128, 64, 2, 1><<<dim3(16, 16), 256, 0, stream>>>(
            hhf, F_, w2 + (size_t)l * D_ * F_, nullptr, nullptr,
            0, 0, D_, x, nullptr);
    }

    rmsnorm_k<<<M_, 256, 0, stream>>>(x, nfw, xn);
    gemm_k<128, 128, 1, 1><<<dim3(250, 16), 256, 0, stream>>>(
        xn, D_, emb, nullptr, nullptr, 0, 0, V_, out, nullptr);
}